// Round 4
// baseline (215.020 us; speedup 1.0000x reference)
//
#include <hip/hip_runtime.h>
#include <math.h>

#define B 8
#define T 128
#define I_TOK 196
#define TEXT_DIM 768
#define IMAGE_DIM 1024
#define HIDDEN 512
#define EXP_SCALE 2.88539008177792681f   // 2*log2(e): exp(2x) = 2^(EXP_SCALE*x)

#define TEXT_TILES (B * T / 4)        // 256
#define IMG_TILES  (B * I_TOK / 4)    // 392

// ---------------- Fused projections v4 ------------------------------------
// 4 rows/block, 256 threads = 2 K-halves x 128 col-groups (4 cols each).
// Register double-buffered W + xs prefetch to break the vmcnt(0)-per-iter
// serialization seen in R3 (VALUBusy 23%). Epilogue prescales by 2*log2(e)
// because pt/pi are consumed ONLY by the scores kernel's exp2.
__global__ __launch_bounds__(256) void proj_kernel(
        const float* __restrict__ text, const float* __restrict__ Wt,
        const float* __restrict__ bt, const float* __restrict__ image,
        const float* __restrict__ Wi, const float* __restrict__ bi,
        float* __restrict__ pt, float* __restrict__ pi)
{
    __shared__ float xs[IMAGE_DIM * 4];   // 16 KB transposed X tile
    __shared__ float part[4 * HIDDEN];    // 8 KB upper-K partials

    const int bid = blockIdx.x;
    const int tid = threadIdx.x;

    const float* X; const float* W; const float* bias; float* Y;
    int K, m0;
    if (bid < TEXT_TILES) {
        X = text; W = Wt; bias = bt; Y = pt; K = TEXT_DIM; m0 = bid * 4;
    } else {
        X = image; W = Wi; bias = bi; Y = pi; K = IMAGE_DIM;
        m0 = (bid - TEXT_TILES) * 4;
    }

    for (int d = tid; d < K; d += 256) {
        float4 v;
        v.x = X[(long)(m0 + 0) * K + d];
        v.y = X[(long)(m0 + 1) * K + d];
        v.z = X[(long)(m0 + 2) * K + d];
        v.w = X[(long)(m0 + 3) * K + d];
        *(float4*)&xs[d * 4] = v;
    }
    __syncthreads();

    const int kh = tid >> 7;
    const int cg = tid & 127;
    const int n  = cg * 4;
    const int Kh = K >> 1;

    const float* Wp = W + (long)kh * Kh * HIDDEN + n;
    const float* xp = xs + (long)kh * Kh * 4;

    float4 acc0 = {0,0,0,0}, acc1 = {0,0,0,0}, acc2 = {0,0,0,0}, acc3 = {0,0,0,0};

#define WLD(d) (*(const float4*)(Wp + (long)(d) * HIDDEN))
#define XLD(d) (*(const float4*)(xp + (d) * 4))
#define PSTEP(xv, wv) \
    acc0.x = fmaf(xv.x, wv.x, acc0.x); acc0.y = fmaf(xv.x, wv.y, acc0.y); \
    acc0.z = fmaf(xv.x, wv.z, acc0.z); acc0.w = fmaf(xv.x, wv.w, acc0.w); \
    acc1.x = fmaf(xv.y, wv.x, acc1.x); acc1.y = fmaf(xv.y, wv.y, acc1.y); \
    acc1.z = fmaf(xv.y, wv.z, acc1.z); acc1.w = fmaf(xv.y, wv.w, acc1.w); \
    acc2.x = fmaf(xv.z, wv.x, acc2.x); acc2.y = fmaf(xv.z, wv.y, acc2.y); \
    acc2.z = fmaf(xv.z, wv.z, acc2.z); acc2.w = fmaf(xv.z, wv.w, acc2.w); \
    acc3.x = fmaf(xv.w, wv.x, acc3.x); acc3.y = fmaf(xv.w, wv.y, acc3.y); \
    acc3.z = fmaf(xv.w, wv.z, acc3.z); acc3.w = fmaf(xv.w, wv.w, acc3.w);

    float4 cw0 = WLD(0), cw1 = WLD(1), cw2 = WLD(2), cw3 = WLD(3);
    float4 cx0 = XLD(0), cx1 = XLD(1), cx2 = XLD(2), cx3 = XLD(3);

    for (int d = 0; d < Kh; d += 4) {
        const int dn = (d + 4 < Kh) ? (d + 4) : 0;
        const float4 nw0 = WLD(dn + 0), nw1 = WLD(dn + 1);
        const float4 nw2 = WLD(dn + 2), nw3 = WLD(dn + 3);
        const float4 nx0 = XLD(dn + 0), nx1 = XLD(dn + 1);
        const float4 nx2 = XLD(dn + 2), nx3 = XLD(dn + 3);
        PSTEP(cx0, cw0) PSTEP(cx1, cw1) PSTEP(cx2, cw2) PSTEP(cx3, cw3)
        cw0 = nw0; cw1 = nw1; cw2 = nw2; cw3 = nw3;
        cx0 = nx0; cx1 = nx1; cx2 = nx2; cx3 = nx3;
    }

    if (kh == 1) {
        *(float4*)&part[0 * HIDDEN + n] = acc0;
        *(float4*)&part[1 * HIDDEN + n] = acc1;
        *(float4*)&part[2 * HIDDEN + n] = acc2;
        *(float4*)&part[3 * HIDDEN + n] = acc3;
    }
    __syncthreads();
    if (kh == 0) {
        const float4 bv = *(const float4*)(bias + n);
        const float4 p0 = *(const float4*)&part[0 * HIDDEN + n];
        const float4 p1 = *(const float4*)&part[1 * HIDDEN + n];
        const float4 p2 = *(const float4*)&part[2 * HIDDEN + n];
        const float4 p3 = *(const float4*)&part[3 * HIDDEN + n];
        float4 o;
        o.x = (acc0.x + p0.x + bv.x) * EXP_SCALE; o.y = (acc0.y + p0.y + bv.y) * EXP_SCALE;
        o.z = (acc0.z + p0.z + bv.z) * EXP_SCALE; o.w = (acc0.w + p0.w + bv.w) * EXP_SCALE;
        *(float4*)(Y + (long)(m0 + 0) * HIDDEN + n) = o;
        o.x = (acc1.x + p1.x + bv.x) * EXP_SCALE; o.y = (acc1.y + p1.y + bv.y) * EXP_SCALE;
        o.z = (acc1.z + p1.z + bv.z) * EXP_SCALE; o.w = (acc1.w + p1.w + bv.w) * EXP_SCALE;
        *(float4*)(Y + (long)(m0 + 1) * HIDDEN + n) = o;
        o.x = (acc2.x + p2.x + bv.x) * EXP_SCALE; o.y = (acc2.y + p2.y + bv.y) * EXP_SCALE;
        o.z = (acc2.z + p2.z + bv.z) * EXP_SCALE; o.w = (acc2.w + p2.w + bv.w) * EXP_SCALE;
        *(float4*)(Y + (long)(m0 + 2) * HIDDEN + n) = o;
        o.x = (acc3.x + p3.x + bv.x) * EXP_SCALE; o.y = (acc3.y + p3.y + bv.y) * EXP_SCALE;
        o.z = (acc3.z + p3.z + bv.z) * EXP_SCALE; o.w = (acc3.w + p3.w + bv.w) * EXP_SCALE;
        *(float4*)(Y + (long)(m0 + 3) * HIDDEN + n) = o;
    }
#undef WLD
#undef XLD
}

// ---------------- Scores v4 ------------------------------------------------
// score[b,t,i] = sum_h wa*tanh(x) + ba  with  wa*tanh(x) = wa - 2*wa/(e^2x+1)
// pt/pi arrive prescaled by 2*log2(e), so e^2x = exp2(pt'+pi').
// Lane owns h = lane*8..lane*8+7 (2x dwordx4 loads). grid = 2*B*T for TLP.
__global__ __launch_bounds__(256, 8) void scores_kernel(const float* __restrict__ pt,
        const float* __restrict__ pi, const float* __restrict__ wa,
        const float* __restrict__ ba, float* __restrict__ scores)
{
    const int blk = blockIdx.x;          // 0..2047
    const int bt = blk >> 1;
    const int half = blk & 1;
    const int b = bt >> 7;               // /T
    const int tid = threadIdx.x;
    const int lane = tid & 63, wave = tid >> 6;

    const float* ptrow = pt + (long)bt * HIDDEN + lane * 8;
    const float4 pA = *(const float4*)ptrow;
    const float4 pB = *(const float4*)(ptrow + 4);
    float4 wA = *(const float4*)(wa + lane * 8);
    float4 wB = *(const float4*)(wa + lane * 8 + 4);

    float S = wA.x + wA.y + wA.z + wA.w + wB.x + wB.y + wB.z + wB.w;
    #pragma unroll
    for (int off = 32; off; off >>= 1) S += __shfl_down(S, off);
    const float base = S + ba[0];        // valid on lane 0 (only consumer)

    wA.x *= -2.f; wA.y *= -2.f; wA.z *= -2.f; wA.w *= -2.f;
    wB.x *= -2.f; wB.y *= -2.f; wB.z *= -2.f; wB.w *= -2.f;

    const float* pib = pi + (long)b * I_TOK * HIDDEN + lane * 8;
    const int i0 = half * 98 + wave;
    const int iend = half * 98 + 98;

    float4 ca = *(const float4*)(pib + (long)i0 * HIDDEN);
    float4 cb = *(const float4*)(pib + (long)i0 * HIDDEN + 4);

    for (int i = i0; i < iend; i += 4) {
        const int inx = (i + 4 < iend) ? (i + 4) : i;
        const float4 na = *(const float4*)(pib + (long)inx * HIDDEN);
        const float4 nb = *(const float4*)(pib + (long)inx * HIDDEN + 4);

        float acc = 0.f;
        acc = fmaf(wA.x, __fdividef(1.f, exp2f(pA.x + ca.x) + 1.f), acc);
        acc = fmaf(wA.y, __fdividef(1.f, exp2f(pA.y + ca.y) + 1.f), acc);
        acc = fmaf(wA.z, __fdividef(1.f, exp2f(pA.z + ca.z) + 1.f), acc);
        acc = fmaf(wA.w, __fdividef(1.f, exp2f(pA.w + ca.w) + 1.f), acc);
        acc = fmaf(wB.x, __fdividef(1.f, exp2f(pB.x + cb.x) + 1.f), acc);
        acc = fmaf(wB.y, __fdividef(1.f, exp2f(pB.y + cb.y) + 1.f), acc);
        acc = fmaf(wB.z, __fdividef(1.f, exp2f(pB.z + cb.z) + 1.f), acc);
        acc = fmaf(wB.w, __fdividef(1.f, exp2f(pB.w + cb.w) + 1.f), acc);

        #pragma unroll
        for (int off = 32; off; off >>= 1) acc += __shfl_down(acc, off);
        if (lane == 0) scores[(long)bt * I_TOK + i] = base + acc;
        ca = na; cb = nb;
    }
}

// ---------------- Fused attended outputs v4 --------------------------------
// blocks [0,512): text_attended — 4 t-rows, col-half; float2 loads + prefetch
// blocks [512,904): image_attended — 4 i-rows; float2+float loads + prefetch
// Softmax weights stored transposed in LDS: one ds_read_b128 broadcast/iter.
__global__ __launch_bounds__(256) void att_kernel(const float* __restrict__ scores,
        const float* __restrict__ image, const float* __restrict__ text,
        float* __restrict__ out_text, float* __restrict__ out_img)
{
    const int tid = threadIdx.x, lane = tid & 63, wave = tid >> 6;

    if (blockIdx.x < 512) {
        const int bid = blockIdx.x;
        const int csplit = bid & 1;
        const int grp = bid >> 1;
        const int b = grp >> 5;
        const int t0 = (grp & 31) * 4;

        __shared__ float ps[I_TOK][4];
        {
            const float* srow = scores + ((long)(b * T + t0 + wave)) * I_TOK;
            const float s0 = srow[lane];
            const float s1 = srow[lane + 64];
            const float s2 = srow[lane + 128];
            const float s3 = (lane < 4) ? srow[lane + 192] : -INFINITY;
            float m = fmaxf(fmaxf(s0, s1), fmaxf(s2, s3));
            #pragma unroll
            for (int off = 32; off; off >>= 1) m = fmaxf(m, __shfl_xor(m, off));
            const float e0 = __expf(s0 - m);
            const float e1 = __expf(s1 - m);
            const float e2 = __expf(s2 - m);
            const float e3 = (lane < 4) ? __expf(s3 - m) : 0.f;
            float sum = e0 + e1 + e2 + e3;
            #pragma unroll
            for (int off = 32; off; off >>= 1) sum += __shfl_xor(sum, off);
            const float inv = __fdividef(1.0f, sum);
            ps[lane][wave] = e0 * inv;
            ps[lane + 64][wave] = e1 * inv;
            ps[lane + 128][wave] = e2 * inv;
            if (lane < 4) ps[lane + 192][wave] = e3 * inv;
        }
        __syncthreads();

        const float* img = image + (long)b * I_TOK * IMAGE_DIM + csplit * 512 + tid * 2;
        float a00 = 0.f, a01 = 0.f, a10 = 0.f, a11 = 0.f;
        float a20 = 0.f, a21 = 0.f, a30 = 0.f, a31 = 0.f;

        float2 v = *(const float2*)img;
        float4 pv = *(const float4*)&ps[0][0];
        for (int i = 0; i < I_TOK; ++i) {
            const int in = (i + 1 < I_TOK) ? (i + 1) : i;
            const float2 vn = *(const float2*)(img + (long)in * IMAGE_DIM);
            const float4 pn = *(const float4*)&ps[in][0];
            a00 = fmaf(pv.x, v.x, a00); a01 = fmaf(pv.x, v.y, a01);
            a10 = fmaf(pv.y, v.x, a10); a11 = fmaf(pv.y, v.y, a11);
            a20 = fmaf(pv.z, v.x, a20); a21 = fmaf(pv.z, v.y, a21);
            a30 = fmaf(pv.w, v.x, a30); a31 = fmaf(pv.w, v.y, a31);
            v = vn; pv = pn;
        }
        float* o = out_text + ((long)(b * T + t0)) * IMAGE_DIM + csplit * 512 + tid * 2;
        float2 w;
        w.x = a00; w.y = a01; *(float2*)(o + 0 * IMAGE_DIM) = w;
        w.x = a10; w.y = a11; *(float2*)(o + 1 * IMAGE_DIM) = w;
        w.x = a20; w.y = a21; *(float2*)(o + 2 * IMAGE_DIM) = w;
        w.x = a30; w.y = a31; *(float2*)(o + 3 * IMAGE_DIM) = w;
    } else {
        const int bid = blockIdx.x - 512;
        const int b = bid / (I_TOK / 4);
        const int i0 = (bid % (I_TOK / 4)) * 4;

        __shared__ float qs[T][4];
        {
            const float* sc = scores + (long)b * T * I_TOK + (i0 + wave);
            const float s0 = sc[(long)lane * I_TOK];
            const float s1 = sc[(long)(lane + 64) * I_TOK];
            float m = fmaxf(s0, s1);
            #pragma unroll
            for (int off = 32; off; off >>= 1) m = fmaxf(m, __shfl_xor(m, off));
            const float e0 = __expf(s0 - m);
            const float e1 = __expf(s1 - m);
            float sum = e0 + e1;
            #pragma unroll
            for (int off = 32; off; off >>= 1) sum += __shfl_xor(sum, off);
            const float inv = __fdividef(1.0f, sum);
            qs[lane][wave] = e0 * inv;
            qs[lane + 64][wave] = e1 * inv;
        }
        __syncthreads();

        const float* txt2 = text + (long)b * T * TEXT_DIM + tid * 2;
        const float* txt1 = text + (long)b * T * TEXT_DIM + 512 + tid;
        float a00=0.f,a01=0.f,a02=0.f, a10=0.f,a11=0.f,a12=0.f;
        float a20=0.f,a21=0.f,a22=0.f, a30=0.f,a31=0.f,a32=0.f;

        float2 v01 = *(const float2*)txt2;
        float v2 = *txt1;
        float4 qv = *(const float4*)&qs[0][0];
        for (int t = 0; t < T; ++t) {
            const int tn = (t + 1 < T) ? (t + 1) : t;
            const float2 vn01 = *(const float2*)(txt2 + (long)tn * TEXT_DIM);
            const float vn2 = txt1[(long)tn * TEXT_DIM];
            const float4 qn = *(const float4*)&qs[tn][0];
            a00 = fmaf(qv.x, v01.x, a00); a01 = fmaf(qv.x, v01.y, a01); a02 = fmaf(qv.x, v2, a02);
            a10 = fmaf(qv.y, v01.x, a10); a11 = fmaf(qv.y, v01.y, a11); a12 = fmaf(qv.y, v2, a12);
            a20 = fmaf(qv.z, v01.x, a20); a21 = fmaf(qv.z, v01.y, a21); a22 = fmaf(qv.z, v2, a22);
            a30 = fmaf(qv.w, v01.x, a30); a31 = fmaf(qv.w, v01.y, a31); a32 = fmaf(qv.w, v2, a32);
            v01 = vn01; v2 = vn2; qv = qn;
        }
        float* o = out_img + ((long)b * I_TOK + i0) * TEXT_DIM;
        float2 w;
        w.x = a00; w.y = a01; *(float2*)(o + 0 * TEXT_DIM + tid * 2) = w; o[0 * TEXT_DIM + 512 + tid] = a02;
        w.x = a10; w.y = a11; *(float2*)(o + 1 * TEXT_DIM + tid * 2) = w; o[1 * TEXT_DIM + 512 + tid] = a12;
        w.x = a20; w.y = a21; *(float2*)(o + 2 * TEXT_DIM + tid * 2) = w; o[2 * TEXT_DIM + 512 + tid] = a22;
        w.x = a30; w.y = a31; *(float2*)(o + 3 * TEXT_DIM + tid * 2) = w; o[3 * TEXT_DIM + 512 + tid] = a32;
    }
}

extern "C" void kernel_launch(void* const* d_in, const int* in_sizes, int n_in,
                              void* d_out, int out_size, void* d_ws, size_t ws_size,
                              hipStream_t stream) {
    const float* text  = (const float*)d_in[0];
    const float* image = (const float*)d_in[1];
    const float* Wt    = (const float*)d_in[2];
    const float* bt    = (const float*)d_in[3];
    const float* Wi    = (const float*)d_in[4];
    const float* bi    = (const float*)d_in[5];
    const float* wa    = (const float*)d_in[6];
    const float* ba    = (const float*)d_in[7];

    float* pt = (float*)d_ws;                       // B*T*HIDDEN (prescaled)
    float* pi = pt + (long)B * T * HIDDEN;          // B*I*HIDDEN (prescaled)
    float* sc = pi + (long)B * I_TOK * HIDDEN;      // B*T*I

    float* out_text = (float*)d_out;                        // B*T*IMAGE_DIM
    float* out_img  = out_text + (long)B * T * IMAGE_DIM;   // B*I*TEXT_DIM

    proj_kernel<<<TEXT_TILES + IMG_TILES, 256, 0, stream>>>(text, Wt, bt, image, Wi, bi, pt, pi);
    scores_kernel<<<2 * B * T, 256, 0, stream>>>(pt, pi, wa, ba, sc);
    att_kernel<<<512 + B * (I_TOK / 4), 256, 0, stream>>>(sc, image, text, out_text, out_img);
}

// Round 5
// 184.357 us; speedup vs baseline: 1.1663x; 1.1663x over previous
//
#include <hip/hip_runtime.h>
#include <math.h>

#define B 8
#define T 128
#define I_TOK 196
#define TEXT_DIM 768
#define IMAGE_DIM 1024
#define HIDDEN 512
#define EXP_SCALE 2.88539008177792681f   // 2*log2(e): exp(2x) = 2^(EXP_SCALE*x)

// Raw HW transcendentals (1 instr each). exp2f/libm without fast-math lowers
// to branchy __ocml code (R4 regression: scores 73->79us). v_exp_f32 IS 2^x.
#if __has_builtin(__builtin_amdgcn_exp2f)
#define FAST_EXP2(x) __builtin_amdgcn_exp2f(x)
#else
#define FAST_EXP2(x) exp2f(x)
#endif
#if __has_builtin(__builtin_amdgcn_rcpf)
#define FAST_RCP(x) __builtin_amdgcn_rcpf(x)
#else
#define FAST_RCP(x) __fdividef(1.f, (x))
#endif

#define ROWS 8
#define ROWTILES_T (B * T / ROWS)       // 128
#define ROWTILES_I (B * I_TOK / ROWS)   // 196
#define PROJ_GRID (2 * (ROWTILES_T + ROWTILES_I))   // 648

// ---------------- Fused projections v5 ------------------------------------
// 8 rows x 256-col half per block (halves W L2 traffic vs 4-row: 610 MB ->
// 17.7us L2 floor). 256 thr = 2 K-halves x 128 col-threads (2 cols each).
// X staged transposed in LDS (xs[d][8]); compute reads are wave-broadcast.
// W double-buffered 4 deep to keep 4 global loads in flight at 2.5 waves/SIMD.
__global__ __launch_bounds__(256) void proj_kernel(
        const float* __restrict__ text, const float* __restrict__ Wt,
        const float* __restrict__ bt, const float* __restrict__ image,
        const float* __restrict__ Wi, const float* __restrict__ bi,
        float* __restrict__ pt, float* __restrict__ pi)
{
    __shared__ float xs[IMAGE_DIM * ROWS];   // 32 KB transposed X tile
    __shared__ float part[ROWS * 256];       // 8 KB upper-K partials

    const int bid = blockIdx.x;
    const int tid = threadIdx.x;

    const float* X; const float* W; const float* bias; float* Y;
    int K, m0, ch;
    if (bid < 2 * ROWTILES_T) {
        X = text; W = Wt; bias = bt; Y = pt; K = TEXT_DIM;
        m0 = (bid >> 1) * ROWS; ch = bid & 1;
    } else {
        const int b2 = bid - 2 * ROWTILES_T;
        X = image; W = Wi; bias = bi; Y = pi; K = IMAGE_DIM;
        m0 = (b2 >> 1) * ROWS; ch = b2 & 1;
    }

    // stage X[m0..m0+7][*] transposed -> xs[d*8 + r]
    for (int d = tid; d < K; d += 256) {
        float4 lo, hi;
        lo.x = X[(long)(m0 + 0) * K + d];
        lo.y = X[(long)(m0 + 1) * K + d];
        lo.z = X[(long)(m0 + 2) * K + d];
        lo.w = X[(long)(m0 + 3) * K + d];
        hi.x = X[(long)(m0 + 4) * K + d];
        hi.y = X[(long)(m0 + 5) * K + d];
        hi.z = X[(long)(m0 + 6) * K + d];
        hi.w = X[(long)(m0 + 7) * K + d];
        *(float4*)&xs[d * 8] = lo;
        *(float4*)&xs[d * 8 + 4] = hi;
    }
    __syncthreads();

    const int kh = tid >> 7;              // K-half (wave-uniform)
    const int cg = tid & 127;             // col group
    const int n  = ch * 256 + cg * 2;     // global col
    const int Kh = K >> 1;

    const float* Wp = W + (long)kh * Kh * HIDDEN + n;
    const float* xp = xs + (long)kh * Kh * 8;

    float2 acc[ROWS];
    #pragma unroll
    for (int r = 0; r < ROWS; ++r) { acc[r].x = 0.f; acc[r].y = 0.f; }

#define WL(d) (*(const float2*)(Wp + (long)(d) * HIDDEN))

    float2 cw0 = WL(0), cw1 = WL(1), cw2 = WL(2), cw3 = WL(3);

    for (int d = 0; d < Kh; d += 4) {
        const int dn = (d + 4 < Kh) ? (d + 4) : 0;
        const float2 nw0 = WL(dn + 0), nw1 = WL(dn + 1);
        const float2 nw2 = WL(dn + 2), nw3 = WL(dn + 3);
        #pragma unroll
        for (int j = 0; j < 4; ++j) {
            const float2 w = (j == 0) ? cw0 : (j == 1) ? cw1 : (j == 2) ? cw2 : cw3;
            const float4 xa = *(const float4*)&xp[(d + j) * 8];
            const float4 xb = *(const float4*)&xp[(d + j) * 8 + 4];
            acc[0].x = fmaf(xa.x, w.x, acc[0].x); acc[0].y = fmaf(xa.x, w.y, acc[0].y);
            acc[1].x = fmaf(xa.y, w.x, acc[1].x); acc[1].y = fmaf(xa.y, w.y, acc[1].y);
            acc[2].x = fmaf(xa.z, w.x, acc[2].x); acc[2].y = fmaf(xa.z, w.y, acc[2].y);
            acc[3].x = fmaf(xa.w, w.x, acc[3].x); acc[3].y = fmaf(xa.w, w.y, acc[3].y);
            acc[4].x = fmaf(xb.x, w.x, acc[4].x); acc[4].y = fmaf(xb.x, w.y, acc[4].y);
            acc[5].x = fmaf(xb.y, w.x, acc[5].x); acc[5].y = fmaf(xb.y, w.y, acc[5].y);
            acc[6].x = fmaf(xb.z, w.x, acc[6].x); acc[6].y = fmaf(xb.z, w.y, acc[6].y);
            acc[7].x = fmaf(xb.w, w.x, acc[7].x); acc[7].y = fmaf(xb.w, w.y, acc[7].y);
        }
        cw0 = nw0; cw1 = nw1; cw2 = nw2; cw3 = nw3;
    }
#undef WL

    if (kh == 1) {
        #pragma unroll
        for (int r = 0; r < ROWS; ++r)
            *(float2*)&part[r * 256 + cg * 2] = acc[r];
    }
    __syncthreads();
    if (kh == 0) {
        const float2 bv = *(const float2*)(bias + n);
        #pragma unroll
        for (int r = 0; r < ROWS; ++r) {
            const float2 p = *(const float2*)&part[r * 256 + cg * 2];
            float2 o;
            o.x = (acc[r].x + p.x + bv.x) * EXP_SCALE;
            o.y = (acc[r].y + p.y + bv.y) * EXP_SCALE;
            *(float2*)(Y + (long)(m0 + r) * HIDDEN + n) = o;
        }
    }
}

// ---------------- Scores v5 ------------------------------------------------
// score = (sum wa + ba) + sum_h -2*wa / (exp2(pt'+pi') + 1); pt'/pi' are
// prescaled by 2*log2(e). Raw v_exp_f32 / v_rcp_f32 via builtins.
__global__ __launch_bounds__(256, 8) void scores_kernel(const float* __restrict__ pt,
        const float* __restrict__ pi, const float* __restrict__ wa,
        const float* __restrict__ ba, float* __restrict__ scores)
{
    const int blk = blockIdx.x;          // 0..2047
    const int bt = blk >> 1;
    const int half = blk & 1;
    const int b = bt >> 7;               // /T
    const int tid = threadIdx.x;
    const int lane = tid & 63, wave = tid >> 6;

    const float* ptrow = pt + (long)bt * HIDDEN + lane * 8;
    const float4 pA = *(const float4*)ptrow;
    const float4 pB = *(const float4*)(ptrow + 4);
    float4 wA = *(const float4*)(wa + lane * 8);
    float4 wB = *(const float4*)(wa + lane * 8 + 4);

    float S = wA.x + wA.y + wA.z + wA.w + wB.x + wB.y + wB.z + wB.w;
    #pragma unroll
    for (int off = 32; off; off >>= 1) S += __shfl_down(S, off);
    const float base = S + ba[0];        // consumed on lane 0 only

    wA.x *= -2.f; wA.y *= -2.f; wA.z *= -2.f; wA.w *= -2.f;
    wB.x *= -2.f; wB.y *= -2.f; wB.z *= -2.f; wB.w *= -2.f;

    const float* pib = pi + (long)b * I_TOK * HIDDEN + lane * 8;
    const int i0 = half * 98 + wave;
    const int iend = half * 98 + 98;

    float4 ca = *(const float4*)(pib + (long)i0 * HIDDEN);
    float4 cb = *(const float4*)(pib + (long)i0 * HIDDEN + 4);

    for (int i = i0; i < iend; i += 4) {
        const int inx = (i + 4 < iend) ? (i + 4) : i;
        const float4 na = *(const float4*)(pib + (long)inx * HIDDEN);
        const float4 nb = *(const float4*)(pib + (long)inx * HIDDEN + 4);

        float acc = 0.f;
        acc = fmaf(wA.x, FAST_RCP(FAST_EXP2(pA.x + ca.x) + 1.f), acc);
        acc = fmaf(wA.y, FAST_RCP(FAST_EXP2(pA.y + ca.y) + 1.f), acc);
        acc = fmaf(wA.z, FAST_RCP(FAST_EXP2(pA.z + ca.z) + 1.f), acc);
        acc = fmaf(wA.w, FAST_RCP(FAST_EXP2(pA.w + ca.w) + 1.f), acc);
        acc = fmaf(wB.x, FAST_RCP(FAST_EXP2(pB.x + cb.x) + 1.f), acc);
        acc = fmaf(wB.y, FAST_RCP(FAST_EXP2(pB.y + cb.y) + 1.f), acc);
        acc = fmaf(wB.z, FAST_RCP(FAST_EXP2(pB.z + cb.z) + 1.f), acc);
        acc = fmaf(wB.w, FAST_RCP(FAST_EXP2(pB.w + cb.w) + 1.f), acc);

        #pragma unroll
        for (int off = 32; off; off >>= 1) acc += __shfl_down(acc, off);
        if (lane == 0) scores[(long)bt * I_TOK + i] = base + acc;
        ca = na; cb = nb;
    }
}

// ---------------- Fused attended outputs v5 --------------------------------
// Unroll x4 with batched loads: 4 outstanding global loads per iteration
// instead of R4's 1-deep serial prefetch chain.
__global__ __launch_bounds__(256) void att_kernel(const float* __restrict__ scores,
        const float* __restrict__ image, const float* __restrict__ text,
        float* __restrict__ out_text, float* __restrict__ out_img)
{
    const int tid = threadIdx.x, lane = tid & 63, wave = tid >> 6;

    if (blockIdx.x < 512) {
        const int bid = blockIdx.x;
        const int csplit = bid & 1;
        const int grp = bid >> 1;
        const int b = grp >> 5;
        const int t0 = (grp & 31) * 4;

        __shared__ float ps[I_TOK][4];
        {
            const float* srow = scores + ((long)(b * T + t0 + wave)) * I_TOK;
            const float s0 = srow[lane];
            const float s1 = srow[lane + 64];
            const float s2 = srow[lane + 128];
            const float s3 = (lane < 4) ? srow[lane + 192] : -INFINITY;
            float m = fmaxf(fmaxf(s0, s1), fmaxf(s2, s3));
            #pragma unroll
            for (int off = 32; off; off >>= 1) m = fmaxf(m, __shfl_xor(m, off));
            const float e0 = __expf(s0 - m);
            const float e1 = __expf(s1 - m);
            const float e2 = __expf(s2 - m);
            const float e3 = (lane < 4) ? __expf(s3 - m) : 0.f;
            float sum = e0 + e1 + e2 + e3;
            #pragma unroll
            for (int off = 32; off; off >>= 1) sum += __shfl_xor(sum, off);
            const float inv = __fdividef(1.0f, sum);
            ps[lane][wave] = e0 * inv;
            ps[lane + 64][wave] = e1 * inv;
            ps[lane + 128][wave] = e2 * inv;
            if (lane < 4) ps[lane + 192][wave] = e3 * inv;
        }
        __syncthreads();

        const float* img = image + (long)b * I_TOK * IMAGE_DIM + csplit * 512 + tid * 2;
        float a00 = 0.f, a01 = 0.f, a10 = 0.f, a11 = 0.f;
        float a20 = 0.f, a21 = 0.f, a30 = 0.f, a31 = 0.f;

        for (int i = 0; i < I_TOK; i += 4) {          // 196 = 49*4
            const float2 v0 = *(const float2*)(img + (long)(i + 0) * IMAGE_DIM);
            const float2 v1 = *(const float2*)(img + (long)(i + 1) * IMAGE_DIM);
            const float2 v2 = *(const float2*)(img + (long)(i + 2) * IMAGE_DIM);
            const float2 v3 = *(const float2*)(img + (long)(i + 3) * IMAGE_DIM);
            const float4 p0 = *(const float4*)&ps[i + 0][0];
            const float4 p1 = *(const float4*)&ps[i + 1][0];
            const float4 p2 = *(const float4*)&ps[i + 2][0];
            const float4 p3 = *(const float4*)&ps[i + 3][0];
            a00 = fmaf(p0.x, v0.x, a00); a01 = fmaf(p0.x, v0.y, a01);
            a10 = fmaf(p0.y, v0.x, a10); a11 = fmaf(p0.y, v0.y, a11);
            a20 = fmaf(p0.z, v0.x, a20); a21 = fmaf(p0.z, v0.y, a21);
            a30 = fmaf(p0.w, v0.x, a30); a31 = fmaf(p0.w, v0.y, a31);
            a00 = fmaf(p1.x, v1.x, a00); a01 = fmaf(p1.x, v1.y, a01);
            a10 = fmaf(p1.y, v1.x, a10); a11 = fmaf(p1.y, v1.y, a11);
            a20 = fmaf(p1.z, v1.x, a20); a21 = fmaf(p1.z, v1.y, a21);
            a30 = fmaf(p1.w, v1.x, a30); a31 = fmaf(p1.w, v1.y, a31);
            a00 = fmaf(p2.x, v2.x, a00); a01 = fmaf(p2.x, v2.y, a01);
            a10 = fmaf(p2.y, v2.x, a10); a11 = fmaf(p2.y, v2.y, a11);
            a20 = fmaf(p2.z, v2.x, a20); a21 = fmaf(p2.z, v2.y, a21);
            a30 = fmaf(p2.w, v2.x, a30); a31 = fmaf(p2.w, v2.y, a31);
            a00 = fmaf(p3.x, v3.x, a00); a01 = fmaf(p3.x, v3.y, a01);
            a10 = fmaf(p3.y, v3.x, a10); a11 = fmaf(p3.y, v3.y, a11);
            a20 = fmaf(p3.z, v3.x, a20); a21 = fmaf(p3.z, v3.y, a21);
            a30 = fmaf(p3.w, v3.x, a30); a31 = fmaf(p3.w, v3.y, a31);
        }
        float* o = out_text + ((long)(b * T + t0)) * IMAGE_DIM + csplit * 512 + tid * 2;
        float2 w;
        w.x = a00; w.y = a01; *(float2*)(o + 0 * IMAGE_DIM) = w;
        w.x = a10; w.y = a11; *(float2*)(o + 1 * IMAGE_DIM) = w;
        w.x = a20; w.y = a21; *(float2*)(o + 2 * IMAGE_DIM) = w;
        w.x = a30; w.y = a31; *(float2*)(o + 3 * IMAGE_DIM) = w;
    } else {
        const int bid = blockIdx.x - 512;
        const int b = bid / (I_TOK / 4);
        const int i0 = (bid % (I_TOK / 4)) * 4;

        __shared__ float qs[T][4];
        {
            const float* sc = scores + (long)b * T * I_TOK + (i0 + wave);
            const float s0 = sc[(long)lane * I_TOK];
            const float s1 = sc[(long)(lane + 64) * I_TOK];
            float m = fmaxf(s0, s1);
            #pragma unroll
            for (int off = 32; off; off >>= 1) m = fmaxf(m, __shfl_xor(m, off));
            const float e0 = __expf(s0 - m);
            const float e1 = __expf(s1 - m);
            float sum = e0 + e1;
            #pragma unroll
            for (int off = 32; off; off >>= 1) sum += __shfl_xor(sum, off);
            const float inv = __fdividef(1.0f, sum);
            qs[lane][wave] = e0 * inv;
            qs[lane + 64][wave] = e1 * inv;
        }
        __syncthreads();

        const float* txt2 = text + (long)b * T * TEXT_DIM + tid * 2;
        const float* txt1 = text + (long)b * T * TEXT_DIM + 512 + tid;
        float a00=0.f,a01=0.f,a02=0.f, a10=0.f,a11=0.f,a12=0.f;
        float a20=0.f,a21=0.f,a22=0.f, a30=0.f,a31=0.f,a32=0.f;

        for (int t = 0; t < T; t += 2) {              // 128 = 64*2
            const float2 u0 = *(const float2*)(txt2 + (long)(t + 0) * TEXT_DIM);
            const float2 u1 = *(const float2*)(txt2 + (long)(t + 1) * TEXT_DIM);
            const float  z0 = txt1[(long)(t + 0) * TEXT_DIM];
            const float  z1 = txt1[(long)(t + 1) * TEXT_DIM];
            const float4 q0 = *(const float4*)&qs[t + 0][0];
            const float4 q1 = *(const float4*)&qs[t + 1][0];
            a00 = fmaf(q0.x, u0.x, a00); a01 = fmaf(q0.x, u0.y, a01); a02 = fmaf(q0.x, z0, a02);
            a10 = fmaf(q0.y, u0.x, a10); a11 = fmaf(q0.y, u0.y, a11); a12 = fmaf(q0.y, z0, a12);
            a20 = fmaf(q0.z, u0.x, a20); a21 = fmaf(q0.z, u0.y, a21); a22 = fmaf(q0.z, z0, a22);
            a30 = fmaf(q0.w, u0.x, a30); a31 = fmaf(q0.w, u0.y, a31); a32 = fmaf(q0.w, z0, a32);
            a00 = fmaf(q1.x, u1.x, a00); a01 = fmaf(q1.x, u1.y, a01); a02 = fmaf(q1.x, z1, a02);
            a10 = fmaf(q1.y, u1.x, a10); a11 = fmaf(q1.y, u1.y, a11); a12 = fmaf(q1.y, z1, a12);
            a20 = fmaf(q1.z, u1.x, a20); a21 = fmaf(q1.z, u1.y, a21); a22 = fmaf(q1.z, z1, a22);
            a30 = fmaf(q1.w, u1.x, a30); a31 = fmaf(q1.w, u1.y, a31); a32 = fmaf(q1.w, z1, a32);
        }
        float* o = out_img + ((long)b * I_TOK + i0) * TEXT_DIM;
        float2 w;
        w.x = a00; w.y = a01; *(float2*)(o + 0 * TEXT_DIM + tid * 2) = w; o[0 * TEXT_DIM + 512 + tid] = a02;
        w.x = a10; w.y = a11; *(float2*)(o + 1 * TEXT_DIM + tid * 2) = w; o[1 * TEXT_DIM + 512 + tid] = a12;
        w.x = a20; w.y = a21; *(float2*)(o + 2 * TEXT_DIM + tid * 2) = w; o[2 * TEXT_DIM + 512 + tid] = a22;
        w.x = a30; w.y = a31; *(float2*)(o + 3 * TEXT_DIM + tid * 2) = w; o[3 * TEXT_DIM + 512 + tid] = a32;
    }
}

extern "C" void kernel_launch(void* const* d_in, const int* in_sizes, int n_in,
                              void* d_out, int out_size, void* d_ws, size_t ws_size,
                              hipStream_t stream) {
    const float* text  = (const float*)d_in[0];
    const float* image = (const float*)d_in[1];
    const float* Wt    = (const float*)d_in[2];
    const float* bt    = (const float*)d_in[3];
    const float* Wi    = (const float*)d_in[4];
    const float* bi    = (const float*)d_in[5];
    const float* wa    = (const float*)d_in[6];
    const float* ba    = (const float*)d_in[7];

    float* pt = (float*)d_ws;                       // B*T*HIDDEN (prescaled)
    float* pi = pt + (long)B * T * HIDDEN;          // B*I*HIDDEN (prescaled)
    float* sc = pi + (long)B * I_TOK * HIDDEN;      // B*T*I

    float* out_text = (float*)d_out;                        // B*T*IMAGE_DIM
    float* out_img  = out_text + (long)B * T * IMAGE_DIM;   // B*I*TEXT_DIM

    proj_kernel<<<PROJ_GRID, 256, 0, stream>>>(text, Wt, bt, image, Wi, bi, pt, pi);
    scores_kernel<<<2 * B * T, 256, 0, stream>>>(pt, pi, wa, ba, sc);
    att_kernel<<<512 + B * (I_TOK / 4), 256, 0, stream>>>(sc, image, text, out_text, out_img);
}

// Round 6
// 176.758 us; speedup vs baseline: 1.2165x; 1.0430x over previous
//
#include <hip/hip_runtime.h>
#include <math.h>

#define B 8
#define T 128
#define I_TOK 196
#define TEXT_DIM 768
#define IMAGE_DIM 1024
#define HIDDEN 512
#define EXP_SCALE 2.88539008177792681f   // 2*log2(e): exp(2x) = 2^(EXP_SCALE*x)

#if __has_builtin(__builtin_amdgcn_exp2f)
#define FAST_EXP2(x) __builtin_amdgcn_exp2f(x)
#else
#define FAST_EXP2(x) exp2f(x)
#endif
#if __has_builtin(__builtin_amdgcn_rcpf)
#define FAST_RCP(x) __builtin_amdgcn_rcpf(x)
#else
#define FAST_RCP(x) __fdividef(1.f, (x))
#endif

#define ROWS 8
#define ROWTILES_T (B * T / ROWS)       // 128
#define ROWTILES_I (B * I_TOK / ROWS)   // 196
#define PROJ_GRID (4 * (ROWTILES_T + ROWTILES_I))   // 1296 blocks ~ 5/CU

// ---------------- Fused projections v6 ------------------------------------
// R5 post-mortem: 648 blocks = grid-limited occupancy (24%), VALUBusy 32%;
// 149k LDS conflicts from transposed staging (stride-8-bank ds_write_b128).
// v6: 8 rows x 128 cols x K-quarter per block -> 1296 blocks (5/CU, LDS
// 32KB caps exactly 5). X staged ROW-major: stride-1 writes (0 conflicts),
// compute reads are wave-uniform b128 broadcasts (kq=tid>>6 wave-uniform).
// Thread = 2 cols: float2 W loads coalesce to 512B/wave. 4-deep W dbuf.
// K-quarter partials reduced through xs (reused) at the end.
__global__ __launch_bounds__(256) void proj_kernel(
        const float* __restrict__ text, const float* __restrict__ Wt,
        const float* __restrict__ bt, const float* __restrict__ image,
        const float* __restrict__ Wi, const float* __restrict__ bi,
        float* __restrict__ pt, float* __restrict__ pi)
{
    __shared__ float xs[IMAGE_DIM * ROWS];   // 32 KB; reused for reduction

    const int bid = blockIdx.x;
    const int tid = threadIdx.x;

    const float* X; const float* W; const float* bias; float* Y;
    int K, m0, c0;
    if (bid < 4 * ROWTILES_T) {
        X = text; W = Wt; bias = bt; Y = pt; K = TEXT_DIM;
        m0 = (bid >> 2) * ROWS; c0 = (bid & 3) * 128;
    } else {
        const int b2 = bid - 4 * ROWTILES_T;
        X = image; W = Wi; bias = bi; Y = pi; K = IMAGE_DIM;
        m0 = (b2 >> 2) * ROWS; c0 = (b2 & 3) * 128;
    }

    // stage X row-major: coalesced float4 global -> stride-1 LDS writes
    const int nf4 = K >> 2;                  // 192 (text) / 256 (image)
    if (tid < nf4) {
        #pragma unroll
        for (int r = 0; r < ROWS; ++r)
            *(float4*)&xs[r * K + tid * 4] =
                *(const float4*)(X + (long)(m0 + r) * K + tid * 4);
    }
    __syncthreads();

    const int kq = tid >> 6;                 // K-quarter (wave-uniform)
    const int ct = tid & 63;
    const int n  = c0 + ct * 2;
    const int Kq = K >> 2;
    const int dbase = kq * Kq;

    const float* Wp = W + (long)dbase * HIDDEN + n;

    float2 acc[ROWS];
    #pragma unroll
    for (int r = 0; r < ROWS; ++r) { acc[r].x = 0.f; acc[r].y = 0.f; }

#define WL(d) (*(const float2*)(Wp + (long)(d) * HIDDEN))

    float2 cw0 = WL(0), cw1 = WL(1), cw2 = WL(2), cw3 = WL(3);

    for (int d = 0; d < Kq; d += 4) {
        const int dn = (d + 4 < Kq) ? (d + 4) : 0;
        const float2 nw0 = WL(dn + 0), nw1 = WL(dn + 1);
        const float2 nw2 = WL(dn + 2), nw3 = WL(dn + 3);
        #pragma unroll
        for (int r = 0; r < ROWS; ++r) {
            const float4 xr = *(const float4*)&xs[r * K + dbase + d];  // broadcast
            acc[r].x = fmaf(xr.x, cw0.x, acc[r].x); acc[r].y = fmaf(xr.x, cw0.y, acc[r].y);
            acc[r].x = fmaf(xr.y, cw1.x, acc[r].x); acc[r].y = fmaf(xr.y, cw1.y, acc[r].y);
            acc[r].x = fmaf(xr.z, cw2.x, acc[r].x); acc[r].y = fmaf(xr.z, cw2.y, acc[r].y);
            acc[r].x = fmaf(xr.w, cw3.x, acc[r].x); acc[r].y = fmaf(xr.w, cw3.y, acc[r].y);
        }
        cw0 = nw0; cw1 = nw1; cw2 = nw2; cw3 = nw3;
    }
#undef WL

    // 4-way K-partial reduction through reused xs (12 KB needed, 24+ free)
    __syncthreads();
    if (kq > 0) {
        #pragma unroll
        for (int r = 0; r < ROWS; ++r)
            *(float2*)&xs[((kq - 1) * ROWS + r) * 128 + ct * 2] = acc[r];
    }
    __syncthreads();
    if (kq == 0) {
        const float2 bv = *(const float2*)(bias + n);
        #pragma unroll
        for (int r = 0; r < ROWS; ++r) {
            float2 s = acc[r];
            #pragma unroll
            for (int q = 0; q < 3; ++q) {
                const float2 p = *(const float2*)&xs[(q * ROWS + r) * 128 + ct * 2];
                s.x += p.x; s.y += p.y;
            }
            float2 o;
            o.x = (s.x + bv.x) * EXP_SCALE;
            o.y = (s.y + bv.y) * EXP_SCALE;
            *(float2*)(Y + (long)(m0 + r) * HIDDEN + n) = o;
        }
    }
}

// ---------------- Scores v6 (unchanged from v5) ----------------------------
__global__ __launch_bounds__(256, 8) void scores_kernel(const float* __restrict__ pt,
        const float* __restrict__ pi, const float* __restrict__ wa,
        const float* __restrict__ ba, float* __restrict__ scores)
{
    const int blk = blockIdx.x;          // 0..2047
    const int bt = blk >> 1;
    const int half = blk & 1;
    const int b = bt >> 7;               // /T
    const int tid = threadIdx.x;
    const int lane = tid & 63, wave = tid >> 6;

    const float* ptrow = pt + (long)bt * HIDDEN + lane * 8;
    const float4 pA = *(const float4*)ptrow;
    const float4 pB = *(const float4*)(ptrow + 4);
    float4 wA = *(const float4*)(wa + lane * 8);
    float4 wB = *(const float4*)(wa + lane * 8 + 4);

    float S = wA.x + wA.y + wA.z + wA.w + wB.x + wB.y + wB.z + wB.w;
    #pragma unroll
    for (int off = 32; off; off >>= 1) S += __shfl_down(S, off);
    const float base = S + ba[0];        // consumed on lane 0 only

    wA.x *= -2.f; wA.y *= -2.f; wA.z *= -2.f; wA.w *= -2.f;
    wB.x *= -2.f; wB.y *= -2.f; wB.z *= -2.f; wB.w *= -2.f;

    const float* pib = pi + (long)b * I_TOK * HIDDEN + lane * 8;
    const int i0 = half * 98 + wave;
    const int iend = half * 98 + 98;

    float4 ca = *(const float4*)(pib + (long)i0 * HIDDEN);
    float4 cb = *(const float4*)(pib + (long)i0 * HIDDEN + 4);

    for (int i = i0; i < iend; i += 4) {
        const int inx = (i + 4 < iend) ? (i + 4) : i;
        const float4 na = *(const float4*)(pib + (long)inx * HIDDEN);
        const float4 nb = *(const float4*)(pib + (long)inx * HIDDEN + 4);

        float acc = 0.f;
        acc = fmaf(wA.x, FAST_RCP(FAST_EXP2(pA.x + ca.x) + 1.f), acc);
        acc = fmaf(wA.y, FAST_RCP(FAST_EXP2(pA.y + ca.y) + 1.f), acc);
        acc = fmaf(wA.z, FAST_RCP(FAST_EXP2(pA.z + ca.z) + 1.f), acc);
        acc = fmaf(wA.w, FAST_RCP(FAST_EXP2(pA.w + ca.w) + 1.f), acc);
        acc = fmaf(wB.x, FAST_RCP(FAST_EXP2(pB.x + cb.x) + 1.f), acc);
        acc = fmaf(wB.y, FAST_RCP(FAST_EXP2(pB.y + cb.y) + 1.f), acc);
        acc = fmaf(wB.z, FAST_RCP(FAST_EXP2(pB.z + cb.z) + 1.f), acc);
        acc = fmaf(wB.w, FAST_RCP(FAST_EXP2(pB.w + cb.w) + 1.f), acc);

        #pragma unroll
        for (int off = 32; off; off >>= 1) acc += __shfl_down(acc, off);
        if (lane == 0) scores[(long)bt * I_TOK + i] = base + acc;
        ca = na; cb = nb;
    }
}

// ---------------- Fused attended outputs v6 --------------------------------
// 2-stage register pipeline: prefetch next 4-row group while FMA-ing the
// current one (doubles in-flight global loads vs v5's batched-only form).
__global__ __launch_bounds__(256) void att_kernel(const float* __restrict__ scores,
        const float* __restrict__ image, const float* __restrict__ text,
        float* __restrict__ out_text, float* __restrict__ out_img)
{
    const int tid = threadIdx.x, lane = tid & 63, wave = tid >> 6;

    if (blockIdx.x < 512) {
        const int bid = blockIdx.x;
        const int csplit = bid & 1;
        const int grp = bid >> 1;
        const int b = grp >> 5;
        const int t0 = (grp & 31) * 4;

        __shared__ float ps[I_TOK][4];
        {
            const float* srow = scores + ((long)(b * T + t0 + wave)) * I_TOK;
            const float s0 = srow[lane];
            const float s1 = srow[lane + 64];
            const float s2 = srow[lane + 128];
            const float s3 = (lane < 4) ? srow[lane + 192] : -INFINITY;
            float m = fmaxf(fmaxf(s0, s1), fmaxf(s2, s3));
            #pragma unroll
            for (int off = 32; off; off >>= 1) m = fmaxf(m, __shfl_xor(m, off));
            const float e0 = __expf(s0 - m);
            const float e1 = __expf(s1 - m);
            const float e2 = __expf(s2 - m);
            const float e3 = (lane < 4) ? __expf(s3 - m) : 0.f;
            float sum = e0 + e1 + e2 + e3;
            #pragma unroll
            for (int off = 32; off; off >>= 1) sum += __shfl_xor(sum, off);
            const float inv = __fdividef(1.0f, sum);
            ps[lane][wave] = e0 * inv;
            ps[lane + 64][wave] = e1 * inv;
            ps[lane + 128][wave] = e2 * inv;
            if (lane < 4) ps[lane + 192][wave] = e3 * inv;
        }
        __syncthreads();

        const float* img = image + (long)b * I_TOK * IMAGE_DIM + csplit * 512 + tid * 2;
        float a00 = 0.f, a01 = 0.f, a10 = 0.f, a11 = 0.f;
        float a20 = 0.f, a21 = 0.f, a30 = 0.f, a31 = 0.f;

        float2 v0 = *(const float2*)(img + 0 * IMAGE_DIM);
        float2 v1 = *(const float2*)(img + 1 * IMAGE_DIM);
        float2 v2 = *(const float2*)(img + 2 * IMAGE_DIM);
        float2 v3 = *(const float2*)(img + 3 * IMAGE_DIM);
        float4 p0 = *(const float4*)&ps[0][0];
        float4 p1 = *(const float4*)&ps[1][0];
        float4 p2 = *(const float4*)&ps[2][0];
        float4 p3 = *(const float4*)&ps[3][0];

        for (int g = 0; g < 49; ++g) {            // 196 = 49*4
            const int ib = (g + 1 < 49) ? (g + 1) * 4 : g * 4;
            const float2 w0 = *(const float2*)(img + (long)(ib + 0) * IMAGE_DIM);
            const float2 w1 = *(const float2*)(img + (long)(ib + 1) * IMAGE_DIM);
            const float2 w2 = *(const float2*)(img + (long)(ib + 2) * IMAGE_DIM);
            const float2 w3 = *(const float2*)(img + (long)(ib + 3) * IMAGE_DIM);
            const float4 r0 = *(const float4*)&ps[ib + 0][0];
            const float4 r1 = *(const float4*)&ps[ib + 1][0];
            const float4 r2 = *(const float4*)&ps[ib + 2][0];
            const float4 r3 = *(const float4*)&ps[ib + 3][0];
            a00 = fmaf(p0.x, v0.x, a00); a01 = fmaf(p0.x, v0.y, a01);
            a10 = fmaf(p0.y, v0.x, a10); a11 = fmaf(p0.y, v0.y, a11);
            a20 = fmaf(p0.z, v0.x, a20); a21 = fmaf(p0.z, v0.y, a21);
            a30 = fmaf(p0.w, v0.x, a30); a31 = fmaf(p0.w, v0.y, a31);
            a00 = fmaf(p1.x, v1.x, a00); a01 = fmaf(p1.x, v1.y, a01);
            a10 = fmaf(p1.y, v1.x, a10); a11 = fmaf(p1.y, v1.y, a11);
            a20 = fmaf(p1.z, v1.x, a20); a21 = fmaf(p1.z, v1.y, a21);
            a30 = fmaf(p1.w, v1.x, a30); a31 = fmaf(p1.w, v1.y, a31);
            a00 = fmaf(p2.x, v2.x, a00); a01 = fmaf(p2.x, v2.y, a01);
            a10 = fmaf(p2.y, v2.x, a10); a11 = fmaf(p2.y, v2.y, a11);
            a20 = fmaf(p2.z, v2.x, a20); a21 = fmaf(p2.z, v2.y, a21);
            a30 = fmaf(p2.w, v2.x, a30); a31 = fmaf(p2.w, v2.y, a31);
            a00 = fmaf(p3.x, v3.x, a00); a01 = fmaf(p3.x, v3.y, a01);
            a10 = fmaf(p3.y, v3.x, a10); a11 = fmaf(p3.y, v3.y, a11);
            a20 = fmaf(p3.z, v3.x, a20); a21 = fmaf(p3.z, v3.y, a21);
            a30 = fmaf(p3.w, v3.x, a30); a31 = fmaf(p3.w, v3.y, a31);
            v0 = w0; v1 = w1; v2 = w2; v3 = w3;
            p0 = r0; p1 = r1; p2 = r2; p3 = r3;
        }
        float* o = out_text + ((long)(b * T + t0)) * IMAGE_DIM + csplit * 512 + tid * 2;
        float2 w;
        w.x = a00; w.y = a01; *(float2*)(o + 0 * IMAGE_DIM) = w;
        w.x = a10; w.y = a11; *(float2*)(o + 1 * IMAGE_DIM) = w;
        w.x = a20; w.y = a21; *(float2*)(o + 2 * IMAGE_DIM) = w;
        w.x = a30; w.y = a31; *(float2*)(o + 3 * IMAGE_DIM) = w;
    } else {
        const int bid = blockIdx.x - 512;
        const int b = bid / (I_TOK / 4);
        const int i0 = (bid % (I_TOK / 4)) * 4;

        __shared__ float qs[T][4];
        {
            const float* sc = scores + (long)b * T * I_TOK + (i0 + wave);
            const float s0 = sc[(long)lane * I_TOK];
            const float s1 = sc[(long)(lane + 64) * I_TOK];
            float m = fmaxf(s0, s1);
            #pragma unroll
            for (int off = 32; off; off >>= 1) m = fmaxf(m, __shfl_xor(m, off));
            const float e0 = __expf(s0 - m);
            const float e1 = __expf(s1 - m);
            float sum = e0 + e1;
            #pragma unroll
            for (int off = 32; off; off >>= 1) sum += __shfl_xor(sum, off);
            const float inv = __fdividef(1.0f, sum);
            qs[lane][wave] = e0 * inv;
            qs[lane + 64][wave] = e1 * inv;
        }
        __syncthreads();

        const float* txt2 = text + (long)b * T * TEXT_DIM + tid * 2;
        const float* txt1 = text + (long)b * T * TEXT_DIM + 512 + tid;
        float a00=0.f,a01=0.f,a02=0.f, a10=0.f,a11=0.f,a12=0.f;
        float a20=0.f,a21=0.f,a22=0.f, a30=0.f,a31=0.f,a32=0.f;

        float2 u0 = *(const float2*)(txt2 + 0 * TEXT_DIM);
        float2 u1 = *(const float2*)(txt2 + 1 * TEXT_DIM);
        float  z0 = txt1[0 * TEXT_DIM];
        float  z1 = txt1[1 * TEXT_DIM];
        float4 q0 = *(const float4*)&qs[0][0];
        float4 q1 = *(const float4*)&qs[1][0];

        for (int g = 0; g < 64; ++g) {            // 128 = 64*2
            const int tb = (g + 1 < 64) ? (g + 1) * 2 : g * 2;
            const float2 nu0 = *(const float2*)(txt2 + (long)(tb + 0) * TEXT_DIM);
            const float2 nu1 = *(const float2*)(txt2 + (long)(tb + 1) * TEXT_DIM);
            const float  nz0 = txt1[(long)(tb + 0) * TEXT_DIM];
            const float  nz1 = txt1[(long)(tb + 1) * TEXT_DIM];
            const float4 nq0 = *(const float4*)&qs[tb + 0][0];
            const float4 nq1 = *(const float4*)&qs[tb + 1][0];
            a00 = fmaf(q0.x, u0.x, a00); a01 = fmaf(q0.x, u0.y, a01); a02 = fmaf(q0.x, z0, a02);
            a10 = fmaf(q0.y, u0.x, a10); a11 = fmaf(q0.y, u0.y, a11); a12 = fmaf(q0.y, z0, a12);
            a20 = fmaf(q0.z, u0.x, a20); a21 = fmaf(q0.z, u0.y, a21); a22 = fmaf(q0.z, z0, a22);
            a30 = fmaf(q0.w, u0.x, a30); a31 = fmaf(q0.w, u0.y, a31); a32 = fmaf(q0.w, z0, a32);
            a00 = fmaf(q1.x, u1.x, a00); a01 = fmaf(q1.x, u1.y, a01); a02 = fmaf(q1.x, z1, a02);
            a10 = fmaf(q1.y, u1.x, a10); a11 = fmaf(q1.y, u1.y, a11); a12 = fmaf(q1.y, z1, a12);
            a20 = fmaf(q1.z, u1.x, a20); a21 = fmaf(q1.z, u1.y, a21); a22 = fmaf(q1.z, z1, a22);
            a30 = fmaf(q1.w, u1.x, a30); a31 = fmaf(q1.w, u1.y, a31); a32 = fmaf(q1.w, z1, a32);
            u0 = nu0; u1 = nu1; z0 = nz0; z1 = nz1; q0 = nq0; q1 = nq1;
        }
        float* o = out_img + ((long)b * I_TOK + i0) * TEXT_DIM;
        float2 w;
        w.x = a00; w.y = a01; *(float2*)(o + 0 * TEXT_DIM + tid * 2) = w; o[0 * TEXT_DIM + 512 + tid] = a02;
        w.x = a10; w.y = a11; *(float2*)(o + 1 * TEXT_DIM + tid * 2) = w; o[1 * TEXT_DIM + 512 + tid] = a12;
        w.x = a20; w.y = a21; *(float2*)(o + 2 * TEXT_DIM + tid * 2) = w; o[2 * TEXT_DIM + 512 + tid] = a22;
        w.x = a30; w.y = a31; *(float2*)(o + 3 * TEXT_DIM + tid * 2) = w; o[3 * TEXT_DIM + 512 + tid] = a32;
    }
}

extern "C" void kernel_launch(void* const* d_in, const int* in_sizes, int n_in,
                              void* d_out, int out_size, void* d_ws, size_t ws_size,
                              hipStream_t stream) {
    const float* text  = (const float*)d_in[0];
    const float* image = (const float*)d_in[1];
    const float* Wt    = (const float*)d_in[2];
    const float* bt    = (const float*)d_in[3];
    const float* Wi    = (const float*)d_in[4];
    const float* bi    = (const float*)d_in[5];
    const float* wa    = (const float*)d_in[6];
    const float* ba    = (const float*)d_in[7];

    float* pt = (float*)d_ws;                       // B*T*HIDDEN (prescaled)
    float* pi = pt + (long)B * T * HIDDEN;          // B*I*HIDDEN (prescaled)
    float* sc = pi + (long)B * I_TOK * HIDDEN;      // B*T*I

    float* out_text = (float*)d_out;                        // B*T*IMAGE_DIM
    float* out_img  = out_text + (long)B * T * IMAGE_DIM;   // B*I*TEXT_DIM

    proj_kernel<<<PROJ_GRID, 256, 0, stream>>>(text, Wt, bt, image, Wi, bi, pt, pi);
    scores_kernel<<<2 * B * T, 256, 0, stream>>>(pt, pi, wa, ba, sc);
    att_kernel<<<512 + B * (I_TOK / 4), 256, 0, stream>>>(sc, image, text, out_text, out_img);
}

// Round 7
// 176.302 us; speedup vs baseline: 1.2196x; 1.0026x over previous
//
#include <hip/hip_runtime.h>
#include <math.h>

#define B 8
#define T 128
#define I_TOK 196
#define TEXT_DIM 768
#define IMAGE_DIM 1024
#define HIDDEN 512
#define EXP_SCALE 2.88539008177792681f   // 2*log2(e): exp(2x) = 2^(EXP_SCALE*x)

#if __has_builtin(__builtin_amdgcn_exp2f)
#define FAST_EXP2(x) __builtin_amdgcn_exp2f(x)
#else
#define FAST_EXP2(x) exp2f(x)
#endif
#if __has_builtin(__builtin_amdgcn_rcpf)
#define FAST_RCP(x) __builtin_amdgcn_rcpf(x)
#else
#define FAST_RCP(x) __fdividef(1.f, (x))
#endif

typedef short bf16x8 __attribute__((ext_vector_type(8)));
typedef float f32x4 __attribute__((ext_vector_type(4)));

#define XT_ELEMS (B * T * TEXT_DIM)        // 786432
#define XI_ELEMS (B * I_TOK * IMAGE_DIM)   // 1605632
#define X_ELEMS  (XT_ELEMS + XI_ELEMS)     // 2392064
#define WT_T_ELEMS (TEXT_DIM * HIDDEN)     // 393216
#define W_ELEMS (WT_T_ELEMS + IMAGE_DIM * HIDDEN)

__device__ __forceinline__ unsigned short f2bf(float x) {
    unsigned int u = __float_as_uint(x);
    unsigned int r = u + 0x7FFFu + ((u >> 16) & 1u);   // RNE
    return (unsigned short)(r >> 16);
}
__device__ __forceinline__ float bf2f(unsigned short h) {
    return __uint_as_float(((unsigned int)h) << 16);
}

// ---------------- prep: split-bf16 conversion ------------------------------
// X -> Xh/Xl row-major [M][K]; W -> WTh/WTl TRANSPOSED [N=512][K] so both
// MFMA operands load as one contiguous b128 (8 bf16) per lane.
#define PREP_XBLK 512
#define WT_TILES_T 48                        // 8 n-groups x 6 k-chunks(128)
#define WT_TILES_I 64                        // 8 x 8
#define PREP_GRID (PREP_XBLK + WT_TILES_T + WT_TILES_I)

__global__ __launch_bounds__(256) void prep_kernel(
        const float* __restrict__ text, const float* __restrict__ image,
        const float* __restrict__ Wt, const float* __restrict__ Wi,
        unsigned short* __restrict__ Xh, unsigned short* __restrict__ Xl,
        unsigned short* __restrict__ WTh, unsigned short* __restrict__ WTl)
{
    const int tid = threadIdx.x;
    if (blockIdx.x < PREP_XBLK) {
        const int nf4 = X_ELEMS / 4;         // 598016
        for (int i = blockIdx.x * 256 + tid; i < nf4; i += PREP_XBLK * 256) {
            float4 v;
            if (i < XT_ELEMS / 4) v = *(const float4*)(text + (long)i * 4);
            else v = *(const float4*)(image + (long)(i - XT_ELEMS / 4) * 4);
            ushort4 h, l;
            h.x = f2bf(v.x); l.x = f2bf(v.x - bf2f(h.x));
            h.y = f2bf(v.y); l.y = f2bf(v.y - bf2f(h.y));
            h.z = f2bf(v.z); l.z = f2bf(v.z - bf2f(h.z));
            h.w = f2bf(v.w); l.w = f2bf(v.w - bf2f(h.w));
            *(ushort4*)(Xh + (long)i * 4) = h;
            *(ushort4*)(Xl + (long)i * 4) = l;
        }
    } else {
        int wb = blockIdx.x - PREP_XBLK;
        const float* W; unsigned short* oh; unsigned short* ol; int K;
        if (wb < WT_TILES_T) { W = Wt; K = TEXT_DIM; oh = WTh; ol = WTl; }
        else { wb -= WT_TILES_T; W = Wi; K = IMAGE_DIM;
               oh = WTh + WT_T_ELEMS; ol = WTl + WT_T_ELEMS; }
        const int n  = (wb & 7) * 64 + (tid & 63);
        const int ks = (wb >> 3) * 128 + (tid >> 6) * 32;
        #pragma unroll
        for (int j8 = 0; j8 < 32; j8 += 8) {
            unsigned int hh[8], ll[8];
            #pragma unroll
            for (int jj = 0; jj < 8; ++jj) {
                const float v = W[(long)(ks + j8 + jj) * HIDDEN + n];
                hh[jj] = f2bf(v);
                ll[jj] = f2bf(v - bf2f((unsigned short)hh[jj]));
            }
            uint4 hv, lv;
            hv.x = hh[0] | (hh[1] << 16); hv.y = hh[2] | (hh[3] << 16);
            hv.z = hh[4] | (hh[5] << 16); hv.w = hh[6] | (hh[7] << 16);
            lv.x = ll[0] | (ll[1] << 16); lv.y = ll[2] | (ll[3] << 16);
            lv.z = ll[4] | (ll[5] << 16); lv.w = ll[6] | (ll[7] << 16);
            *(uint4*)(oh + (long)n * K + ks + j8) = hv;
            *(uint4*)(ol + (long)n * K + ks + j8) = lv;
        }
    }
}

// ---------------- MFMA projections -----------------------------------------
// 128 thr = 2 waves; block tile M=32 x N=64; wave tile 32x32 = 2x2 mfma
// 16x16x32 tiles. Split-bf16: acc += Ah*Bh + Ah*Bl + Al*Bh (err ~2^-18).
// No LDS: A frag = Xh[(m0+r16)*K + quad*8 + k0] (one b128/lane);
// B frag = WTh[(n0+r16)*K + quad*8 + k0]. Epilogue: col=lane&15,
// row=quad*4+reg (m89-verified C/D layout), +bias, *EXP_SCALE.
#define GT_BLOCKS (32 * 8)                   // text: 1024/32 M x 512/64 N
#define GI_BLOCKS (49 * 8)                   // image: 1568/32 M x 8 N
#define GEMM_GRID (GT_BLOCKS + GI_BLOCKS)    // 648

__global__ __launch_bounds__(128) void mfma_proj_kernel(
        const unsigned short* __restrict__ Xh, const unsigned short* __restrict__ Xl,
        const unsigned short* __restrict__ WTh, const unsigned short* __restrict__ WTl,
        const float* __restrict__ bt, const float* __restrict__ bi,
        float* __restrict__ pt, float* __restrict__ pi)
{
    const int tid = threadIdx.x;
    const int lane = tid & 63, wv = tid >> 6;
    const int r16 = lane & 15, quad = lane >> 4;

    int bid = blockIdx.x;
    const unsigned short *xh, *xl, *wh, *wl; const float* bias; float* Y; int K;
    if (bid < GT_BLOCKS) {
        xh = Xh; xl = Xl; wh = WTh; wl = WTl; bias = bt; Y = pt; K = TEXT_DIM;
    } else {
        bid -= GT_BLOCKS;
        xh = Xh + XT_ELEMS; xl = Xl + XT_ELEMS;
        wh = WTh + WT_T_ELEMS; wl = WTl + WT_T_ELEMS;
        bias = bi; Y = pi; K = IMAGE_DIM;
    }
    const int m0 = (bid >> 3) * 32;
    const int n0 = (bid & 7) * 64 + wv * 32;

    const unsigned short* pah = xh + (long)(m0 + r16) * K + quad * 8;
    const unsigned short* pal = xl + (long)(m0 + r16) * K + quad * 8;
    const unsigned short* pbh = wh + (long)(n0 + r16) * K + quad * 8;
    const unsigned short* pbl = wl + (long)(n0 + r16) * K + quad * 8;
    const long rstep = (long)16 * K;

    f32x4 a00 = {0,0,0,0}, a01 = {0,0,0,0}, a10 = {0,0,0,0}, a11 = {0,0,0,0};

    for (int k0 = 0; k0 < K; k0 += 32) {
        const bf16x8 Ah0 = *(const bf16x8*)(pah + k0);
        const bf16x8 Ah1 = *(const bf16x8*)(pah + rstep + k0);
        const bf16x8 Al0 = *(const bf16x8*)(pal + k0);
        const bf16x8 Al1 = *(const bf16x8*)(pal + rstep + k0);
        const bf16x8 Bh0 = *(const bf16x8*)(pbh + k0);
        const bf16x8 Bh1 = *(const bf16x8*)(pbh + rstep + k0);
        const bf16x8 Bl0 = *(const bf16x8*)(pbl + k0);
        const bf16x8 Bl1 = *(const bf16x8*)(pbl + rstep + k0);

        a00 = __builtin_amdgcn_mfma_f32_16x16x32_bf16(Ah0, Bh0, a00, 0, 0, 0);
        a01 = __builtin_amdgcn_mfma_f32_16x16x32_bf16(Ah0, Bh1, a01, 0, 0, 0);
        a10 = __builtin_amdgcn_mfma_f32_16x16x32_bf16(Ah1, Bh0, a10, 0, 0, 0);
        a11 = __builtin_amdgcn_mfma_f32_16x16x32_bf16(Ah1, Bh1, a11, 0, 0, 0);
        a00 = __builtin_amdgcn_mfma_f32_16x16x32_bf16(Ah0, Bl0, a00, 0, 0, 0);
        a01 = __builtin_amdgcn_mfma_f32_16x16x32_bf16(Ah0, Bl1, a01, 0, 0, 0);
        a10 = __builtin_amdgcn_mfma_f32_16x16x32_bf16(Ah1, Bl0, a10, 0, 0, 0);
        a11 = __builtin_amdgcn_mfma_f32_16x16x32_bf16(Ah1, Bl1, a11, 0, 0, 0);
        a00 = __builtin_amdgcn_mfma_f32_16x16x32_bf16(Al0, Bh0, a00, 0, 0, 0);
        a01 = __builtin_amdgcn_mfma_f32_16x16x32_bf16(Al0, Bh1, a01, 0, 0, 0);
        a10 = __builtin_amdgcn_mfma_f32_16x16x32_bf16(Al1, Bh0, a10, 0, 0, 0);
        a11 = __builtin_amdgcn_mfma_f32_16x16x32_bf16(Al1, Bh1, a11, 0, 0, 0);
    }

    const int row0 = m0 + quad * 4;
    const float bv0 = bias[n0 + r16];
    const float bv1 = bias[n0 + 16 + r16];
    #pragma unroll
    for (int r = 0; r < 4; ++r) {
        Y[(long)(row0 + r)      * HIDDEN + n0 + r16]      = (a00[r] + bv0) * EXP_SCALE;
        Y[(long)(row0 + r)      * HIDDEN + n0 + 16 + r16] = (a01[r] + bv1) * EXP_SCALE;
        Y[(long)(row0 + 16 + r) * HIDDEN + n0 + r16]      = (a10[r] + bv0) * EXP_SCALE;
        Y[(long)(row0 + 16 + r) * HIDDEN + n0 + 16 + r16] = (a11[r] + bv1) * EXP_SCALE;
    }
}

// ---------------- Scores (unchanged from v6) -------------------------------
__global__ __launch_bounds__(256, 8) void scores_kernel(const float* __restrict__ pt,
        const float* __restrict__ pi, const float* __restrict__ wa,
        const float* __restrict__ ba, float* __restrict__ scores)
{
    const int blk = blockIdx.x;
    const int bt = blk >> 1;
    const int half = blk & 1;
    const int b = bt >> 7;
    const int tid = threadIdx.x;
    const int lane = tid & 63, wave = tid >> 6;

    const float* ptrow = pt + (long)bt * HIDDEN + lane * 8;
    const float4 pA = *(const float4*)ptrow;
    const float4 pB = *(const float4*)(ptrow + 4);
    float4 wA = *(const float4*)(wa + lane * 8);
    float4 wB = *(const float4*)(wa + lane * 8 + 4);

    float S = wA.x + wA.y + wA.z + wA.w + wB.x + wB.y + wB.z + wB.w;
    #pragma unroll
    for (int off = 32; off; off >>= 1) S += __shfl_down(S, off);
    const float base = S + ba[0];

    wA.x *= -2.f; wA.y *= -2.f; wA.z *= -2.f; wA.w *= -2.f;
    wB.x *= -2.f; wB.y *= -2.f; wB.z *= -2.f; wB.w *= -2.f;

    const float* pib = pi + (long)b * I_TOK * HIDDEN + lane * 8;
    const int i0 = half * 98 + wave;
    const int iend = half * 98 + 98;

    float4 ca = *(const float4*)(pib + (long)i0 * HIDDEN);
    float4 cb = *(const float4*)(pib + (long)i0 * HIDDEN + 4);

    for (int i = i0; i < iend; i += 4) {
        const int inx = (i + 4 < iend) ? (i + 4) : i;
        const float4 na = *(const float4*)(pib + (long)inx * HIDDEN);
        const float4 nb = *(const float4*)(pib + (long)inx * HIDDEN + 4);

        float acc = 0.f;
        acc = fmaf(wA.x, FAST_RCP(FAST_EXP2(pA.x + ca.x) + 1.f), acc);
        acc = fmaf(wA.y, FAST_RCP(FAST_EXP2(pA.y + ca.y) + 1.f), acc);
        acc = fmaf(wA.z, FAST_RCP(FAST_EXP2(pA.z + ca.z) + 1.f), acc);
        acc = fmaf(wA.w, FAST_RCP(FAST_EXP2(pA.w + ca.w) + 1.f), acc);
        acc = fmaf(wB.x, FAST_RCP(FAST_EXP2(pB.x + cb.x) + 1.f), acc);
        acc = fmaf(wB.y, FAST_RCP(FAST_EXP2(pB.y + cb.y) + 1.f), acc);
        acc = fmaf(wB.z, FAST_RCP(FAST_EXP2(pB.z + cb.z) + 1.f), acc);
        acc = fmaf(wB.w, FAST_RCP(FAST_EXP2(pB.w + cb.w) + 1.f), acc);

        #pragma unroll
        for (int off = 32; off; off >>= 1) acc += __shfl_down(acc, off);
        if (lane == 0) scores[(long)bt * I_TOK + i] = base + acc;
        ca = na; cb = nb;
    }
}

// ---------------- Fused attended outputs (unchanged from v6) ---------------
__global__ __launch_bounds__(256) void att_kernel(const float* __restrict__ scores,
        const float* __restrict__ image, const float* __restrict__ text,
        float* __restrict__ out_text, float* __restrict__ out_img)
{
    const int tid = threadIdx.x, lane = tid & 63, wave = tid >> 6;

    if (blockIdx.x < 512) {
        const int bid = blockIdx.x;
        const int csplit = bid & 1;
        const int grp = bid >> 1;
        const int b = grp >> 5;
        const int t0 = (grp & 31) * 4;

        __shared__ float ps[I_TOK][4];
        {
            const float* srow = scores + ((long)(b * T + t0 + wave)) * I_TOK;
            const float s0 = srow[lane];
            const float s1 = srow[lane + 64];
            const float s2 = srow[lane + 128];
            const float s3 = (lane < 4) ? srow[lane + 192] : -INFINITY;
            float m = fmaxf(fmaxf(s0, s1), fmaxf(s2, s3));
            #pragma unroll
            for (int off = 32; off; off >>= 1) m = fmaxf(m, __shfl_xor(m, off));
            const float e0 = __expf(s0 - m);
            const float e1 = __expf(s1 - m);
            const float e2 = __expf(s2 - m);
            const float e3 = (lane < 4) ? __expf(s3 - m) : 0.f;
            float sum = e0 + e1 + e2 + e3;
            #pragma unroll
            for (int off = 32; off; off >>= 1) sum += __shfl_xor(sum, off);
            const float inv = __fdividef(1.0f, sum);
            ps[lane][wave] = e0 * inv;
            ps[lane + 64][wave] = e1 * inv;
            ps[lane + 128][wave] = e2 * inv;
            if (lane < 4) ps[lane + 192][wave] = e3 * inv;
        }
        __syncthreads();

        const float* img = image + (long)b * I_TOK * IMAGE_DIM + csplit * 512 + tid * 2;
        float a00 = 0.f, a01 = 0.f, a10 = 0.f, a11 = 0.f;
        float a20 = 0.f, a21 = 0.f, a30 = 0.f, a31 = 0.f;

        float2 v0 = *(const float2*)(img + 0 * IMAGE_DIM);
        float2 v1 = *(const float2*)(img + 1 * IMAGE_DIM);
        float2 v2 = *(const float2*)(img + 2 * IMAGE_DIM);
        float2 v3 = *(const float2*)(img + 3 * IMAGE_DIM);
        float4 p0 = *(const float4*)&ps[0][0];
        float4 p1 = *(const float4*)&ps[1][0];
        float4 p2 = *(const float4*)&ps[2][0];
        float4 p3 = *(const float4*)&ps[3][0];

        for (int g = 0; g < 49; ++g) {
            const int ib = (g + 1 < 49) ? (g + 1) * 4 : g * 4;
            const float2 w0 = *(const float2*)(img + (long)(ib + 0) * IMAGE_DIM);
            const float2 w1 = *(const float2*)(img + (long)(ib + 1) * IMAGE_DIM);
            const float2 w2 = *(const float2*)(img + (long)(ib + 2) * IMAGE_DIM);
            const float2 w3 = *(const float2*)(img + (long)(ib + 3) * IMAGE_DIM);
            const float4 r0 = *(const float4*)&ps[ib + 0][0];
            const float4 r1 = *(const float4*)&ps[ib + 1][0];
            const float4 r2 = *(const float4*)&ps[ib + 2][0];
            const float4 r3 = *(const float4*)&ps[ib + 3][0];
            a00 = fmaf(p0.x, v0.x, a00); a01 = fmaf(p0.x, v0.y, a01);
            a10 = fmaf(p0.y, v0.x, a10); a11 = fmaf(p0.y, v0.y, a11);
            a20 = fmaf(p0.z, v0.x, a20); a21 = fmaf(p0.z, v0.y, a21);
            a30 = fmaf(p0.w, v0.x, a30); a31 = fmaf(p0.w, v0.y, a31);
            a00 = fmaf(p1.x, v1.x, a00); a01 = fmaf(p1.x, v1.y, a01);
            a10 = fmaf(p1.y, v1.x, a10); a11 = fmaf(p1.y, v1.y, a11);
            a20 = fmaf(p1.z, v1.x, a20); a21 = fmaf(p1.z, v1.y, a21);
            a30 = fmaf(p1.w, v1.x, a30); a31 = fmaf(p1.w, v1.y, a31);
            a00 = fmaf(p2.x, v2.x, a00); a01 = fmaf(p2.x, v2.y, a01);
            a10 = fmaf(p2.y, v2.x, a10); a11 = fmaf(p2.y, v2.y, a11);
            a20 = fmaf(p2.z, v2.x, a20); a21 = fmaf(p2.z, v2.y, a21);
            a30 = fmaf(p2.w, v2.x, a30); a31 = fmaf(p2.w, v2.y, a31);
            a00 = fmaf(p3.x, v3.x, a00); a01 = fmaf(p3.x, v3.y, a01);
            a10 = fmaf(p3.y, v3.x, a10); a11 = fmaf(p3.y, v3.y, a11);
            a20 = fmaf(p3.z, v3.x, a20); a21 = fmaf(p3.z, v3.y, a21);
            a30 = fmaf(p3.w, v3.x, a30); a31 = fmaf(p3.w, v3.y, a31);
            v0 = w0; v1 = w1; v2 = w2; v3 = w3;
            p0 = r0; p1 = r1; p2 = r2; p3 = r3;
        }
        float* o = out_text + ((long)(b * T + t0)) * IMAGE_DIM + csplit * 512 + tid * 2;
        float2 w;
        w.x = a00; w.y = a01; *(float2*)(o + 0 * IMAGE_DIM) = w;
        w.x = a10; w.y = a11; *(float2*)(o + 1 * IMAGE_DIM) = w;
        w.x = a20; w.y = a21; *(float2*)(o + 2 * IMAGE_DIM) = w;
        w.x = a30; w.y = a31; *(float2*)(o + 3 * IMAGE_DIM) = w;
    } else {
        const int bid = blockIdx.x - 512;
        const int b = bid / (I_TOK / 4);
        const int i0 = (bid % (I_TOK / 4)) * 4;

        __shared__ float qs[T][4];
        {
            const float* sc = scores + (long)b * T * I_TOK + (i0 + wave);
            const float s0 = sc[(long)lane * I_TOK];
            const float s1 = sc[(long)(lane + 64) * I_TOK];
            float m = fmaxf(s0, s1);
            #pragma unroll
            for (int off = 32; off; off >>= 1) m = fmaxf(m, __shfl_xor(m, off));
            const float e0 = __expf(s0 - m);
            const float e1 = __expf(s1 - m);
            float sum = e0 + e1;
            #pragma unroll
            for (int off = 32; off; off >>= 1) sum += __shfl_xor(sum, off);
            const float inv = __fdividef(1.0f, sum);
            qs[lane][wave] = e0 * inv;
            qs[lane + 64][wave] = e1 * inv;
        }
        __syncthreads();

        const float* txt2 = text + (long)b * T * TEXT_DIM + tid * 2;
        const float* txt1 = text + (long)b * T * TEXT_DIM + 512 + tid;
        float a00=0.f,a01=0.f,a02=0.f, a10=0.f,a11=0.f,a12=0.f;
        float a20=0.f,a21=0.f,a22=0.f, a30=0.f,a31=0.f,a32=0.f;

        float2 u0 = *(const float2*)(txt2 + 0 * TEXT_DIM);
        float2 u1 = *(const float2*)(txt2 + 1 * TEXT_DIM);
        float  z0 = txt1[0 * TEXT_DIM];
        float  z1 = txt1[1 * TEXT_DIM];
        float4 q0 = *(const float4*)&qs[0][0];
        float4 q1 = *(const float4*)&qs[1][0];

        for (int g = 0; g < 64; ++g) {
            const int tb = (g + 1 < 64) ? (g + 1) * 2 : g * 2;
            const float2 nu0 = *(const float2*)(txt2 + (long)(tb + 0) * TEXT_DIM);
            const float2 nu1 = *(const float2*)(txt2 + (long)(tb + 1) * TEXT_DIM);
            const float  nz0 = txt1[(long)(tb + 0) * TEXT_DIM];
            const float  nz1 = txt1[(long)(tb + 1) * TEXT_DIM];
            const float4 nq0 = *(const float4*)&qs[tb + 0][0];
            const float4 nq1 = *(const float4*)&qs[tb + 1][0];
            a00 = fmaf(q0.x, u0.x, a00); a01 = fmaf(q0.x, u0.y, a01); a02 = fmaf(q0.x, z0, a02);
            a10 = fmaf(q0.y, u0.x, a10); a11 = fmaf(q0.y, u0.y, a11); a12 = fmaf(q0.y, z0, a12);
            a20 = fmaf(q0.z, u0.x, a20); a21 = fmaf(q0.z, u0.y, a21); a22 = fmaf(q0.z, z0, a22);
            a30 = fmaf(q0.w, u0.x, a30); a31 = fmaf(q0.w, u0.y, a31); a32 = fmaf(q0.w, z0, a32);
            a00 = fmaf(q1.x, u1.x, a00); a01 = fmaf(q1.x, u1.y, a01); a02 = fmaf(q1.x, z1, a02);
            a10 = fmaf(q1.y, u1.x, a10); a11 = fmaf(q1.y, u1.y, a11); a12 = fmaf(q1.y, z1, a12);
            a20 = fmaf(q1.z, u1.x, a20); a21 = fmaf(q1.z, u1.y, a21); a22 = fmaf(q1.z, z1, a22);
            a30 = fmaf(q1.w, u1.x, a30); a31 = fmaf(q1.w, u1.y, a31); a32 = fmaf(q1.w, z1, a32);
            u0 = nu0; u1 = nu1; z0 = nz0; z1 = nz1; q0 = nq0; q1 = nq1;
        }
        float* o = out_img + ((long)b * I_TOK + i0) * TEXT_DIM;
        float2 w;
        w.x = a00; w.y = a01; *(float2*)(o + 0 * TEXT_DIM + tid * 2) = w; o[0 * TEXT_DIM + 512 + tid] = a02;
        w.x = a10; w.y = a11; *(float2*)(o + 1 * TEXT_DIM + tid * 2) = w; o[1 * TEXT_DIM + 512 + tid] = a12;
        w.x = a20; w.y = a21; *(float2*)(o + 2 * TEXT_DIM + tid * 2) = w; o[2 * TEXT_DIM + 512 + tid] = a22;
        w.x = a30; w.y = a31; *(float2*)(o + 3 * TEXT_DIM + tid * 2) = w; o[3 * TEXT_DIM + 512 + tid] = a32;
    }
}

extern "C" void kernel_launch(void* const* d_in, const int* in_sizes, int n_in,
                              void* d_out, int out_size, void* d_ws, size_t ws_size,
                              hipStream_t stream) {
    const float* text  = (const float*)d_in[0];
    const float* image = (const float*)d_in[1];
    const float* Wt    = (const float*)d_in[2];
    const float* bt    = (const float*)d_in[3];
    const float* Wi    = (const float*)d_in[4];
    const float* bi    = (const float*)d_in[5];
    const float* wa    = (const float*)d_in[6];
    const float* ba    = (const float*)d_in[7];

    float* pt = (float*)d_ws;                       // 524288 f (prescaled)
    float* pi = pt + (long)B * T * HIDDEN;          // 802816 f (prescaled)
    float* sc = pi + (long)B * I_TOK * HIDDEN;      // 200704 f
    unsigned short* Xh  = (unsigned short*)(sc + (long)B * T * I_TOK);
    unsigned short* Xl  = Xh + X_ELEMS;
    unsigned short* WTh = Xl + X_ELEMS;
    unsigned short* WTl = WTh + W_ELEMS;            // total ~19.4 MB

    float* out_text = (float*)d_out;                        // B*T*IMAGE_DIM
    float* out_img  = out_text + (long)B * T * IMAGE_DIM;   // B*I*TEXT_DIM

    prep_kernel<<<PREP_GRID, 256, 0, stream>>>(text, image, Wt, Wi, Xh, Xl, WTh, WTl);
    mfma_proj_kernel<<<GEMM_GRID, 128, 0, stream>>>(Xh, Xl, WTh, WTl, bt, bi, pt, pi);
    scores_kernel<<<2 * B * T, 256, 0, stream>>>(pt, pi, wa, ba, sc);
    att_kernel<<<512 + B * (I_TOK / 4), 256, 0, stream>>>(sc, image, text, out_text, out_img);
}

// Round 8
// 167.675 us; speedup vs baseline: 1.2824x; 1.0514x over previous
//
#include <hip/hip_runtime.h>
#include <math.h>

#define B 8
#define T 128
#define I_TOK 196
#define TEXT_DIM 768
#define IMAGE_DIM 1024
#define HIDDEN 512
#define EXP_SCALE 2.88539008177792681f   // 2*log2(e): exp(2x) = 2^(EXP_SCALE*x)

#if __has_builtin(__builtin_amdgcn_exp2f)
#define FAST_EXP2(x) __builtin_amdgcn_exp2f(x)
#else
#define FAST_EXP2(x) exp2f(x)
#endif
#if __has_builtin(__builtin_amdgcn_rcpf)
#define FAST_RCP(x) __builtin_amdgcn_rcpf(x)
#else
#define FAST_RCP(x) __fdividef(1.f, (x))
#endif

typedef short bf16x8 __attribute__((ext_vector_type(8)));
typedef float f32x4 __attribute__((ext_vector_type(4)));

#define XT_ELEMS (B * T * TEXT_DIM)        // 786432
#define XI_ELEMS (B * I_TOK * IMAGE_DIM)   // 1605632
#define X_ELEMS  (XT_ELEMS + XI_ELEMS)     // 2392064
#define WT_T_ELEMS (TEXT_DIM * HIDDEN)     // 393216
#define W_ELEMS (WT_T_ELEMS + IMAGE_DIM * HIDDEN)

__device__ __forceinline__ unsigned short f2bf(float x) {
    unsigned int u = __float_as_uint(x);
    unsigned int r = u + 0x7FFFu + ((u >> 16) & 1u);   // RNE
    return (unsigned short)(r >> 16);
}
__device__ __forceinline__ float bf2f(unsigned short h) {
    return __uint_as_float(((unsigned int)h) << 16);
}

// ---------------- prep: split-bf16 conversion (unchanged from R7) ----------
#define PREP_XBLK 512
#define WT_TILES_T 48
#define WT_TILES_I 64
#define PREP_GRID (PREP_XBLK + WT_TILES_T + WT_TILES_I)

__global__ __launch_bounds__(256) void prep_kernel(
        const float* __restrict__ text, const float* __restrict__ image,
        const float* __restrict__ Wt, const float* __restrict__ Wi,
        unsigned short* __restrict__ Xh, unsigned short* __restrict__ Xl,
        unsigned short* __restrict__ WTh, unsigned short* __restrict__ WTl)
{
    const int tid = threadIdx.x;
    if (blockIdx.x < PREP_XBLK) {
        const int nf4 = X_ELEMS / 4;
        for (int i = blockIdx.x * 256 + tid; i < nf4; i += PREP_XBLK * 256) {
            float4 v;
            if (i < XT_ELEMS / 4) v = *(const float4*)(text + (long)i * 4);
            else v = *(const float4*)(image + (long)(i - XT_ELEMS / 4) * 4);
            ushort4 h, l;
            h.x = f2bf(v.x); l.x = f2bf(v.x - bf2f(h.x));
            h.y = f2bf(v.y); l.y = f2bf(v.y - bf2f(h.y));
            h.z = f2bf(v.z); l.z = f2bf(v.z - bf2f(h.z));
            h.w = f2bf(v.w); l.w = f2bf(v.w - bf2f(h.w));
            *(ushort4*)(Xh + (long)i * 4) = h;
            *(ushort4*)(Xl + (long)i * 4) = l;
        }
    } else {
        int wb = blockIdx.x - PREP_XBLK;
        const float* W; unsigned short* oh; unsigned short* ol; int K;
        if (wb < WT_TILES_T) { W = Wt; K = TEXT_DIM; oh = WTh; ol = WTl; }
        else { wb -= WT_TILES_T; W = Wi; K = IMAGE_DIM;
               oh = WTh + WT_T_ELEMS; ol = WTl + WT_T_ELEMS; }
        const int n  = (wb & 7) * 64 + (tid & 63);
        const int ks = (wb >> 3) * 128 + (tid >> 6) * 32;
        #pragma unroll
        for (int j8 = 0; j8 < 32; j8 += 8) {
            unsigned int hh[8], ll[8];
            #pragma unroll
            for (int jj = 0; jj < 8; ++jj) {
                const float v = W[(long)(ks + j8 + jj) * HIDDEN + n];
                hh[jj] = f2bf(v);
                ll[jj] = f2bf(v - bf2f((unsigned short)hh[jj]));
            }
            uint4 hv, lv;
            hv.x = hh[0] | (hh[1] << 16); hv.y = hh[2] | (hh[3] << 16);
            hv.z = hh[4] | (hh[5] << 16); hv.w = hh[6] | (hh[7] << 16);
            lv.x = ll[0] | (ll[1] << 16); lv.y = ll[2] | (ll[3] << 16);
            lv.z = ll[4] | (ll[5] << 16); lv.w = ll[6] | (ll[7] << 16);
            *(uint4*)(oh + (long)n * K + ks + j8) = hv;
            *(uint4*)(ol + (long)n * K + ks + j8) = lv;
        }
    }
}

// ---------------- MFMA projections v8 --------------------------------------
// R7 post-mortem: MfmaUtil 5.5%, Occ 10% -> 1.27 waves/SIMD with no prefetch
// = vmem-latency bound. v8: 256-thr blocks = 4 waves = {2 n-subtiles} x
// {2 K-halves} -> 2592 waves (2.53/SIMD, 2x TLP) + D=2 register prefetch
// (2x ILP). K-halves combined via LDS (stride 66 kills quad-bank aliasing).
// Epilogue stores Et = exp2(EXP_SCALE*(acc+bias)) so the scores kernel can
// use exp2(a+b) = exp2(a)*exp2(b) and skip its per-element exp.
#define GT_BLOCKS (32 * 8)
#define GI_BLOCKS (49 * 8)
#define GEMM_GRID (GT_BLOCKS + GI_BLOCKS)    // 648
#define PSTRIDE 66

__global__ __launch_bounds__(256) void mfma_proj_kernel(
        const unsigned short* __restrict__ Xh, const unsigned short* __restrict__ Xl,
        const unsigned short* __restrict__ WTh, const unsigned short* __restrict__ WTl,
        const float* __restrict__ bt, const float* __restrict__ bi,
        float* __restrict__ pt, float* __restrict__ pi)
{
    __shared__ float part[32 * PSTRIDE];     // 8.4 KB K-half partials

    const int tid = threadIdx.x;
    const int lane = tid & 63, wv = tid >> 6;
    const int r16 = lane & 15, quad = lane >> 4;
    const int nh = wv & 1;                   // n-subtile
    const int kh = wv >> 1;                  // K-half

    int bid = blockIdx.x;
    const unsigned short *xh, *xl, *wh, *wl; const float* bias; float* Y; int K;
    if (bid < GT_BLOCKS) {
        xh = Xh; xl = Xl; wh = WTh; wl = WTl; bias = bt; Y = pt; K = TEXT_DIM;
    } else {
        bid -= GT_BLOCKS;
        xh = Xh + XT_ELEMS; xl = Xl + XT_ELEMS;
        wh = WTh + WT_T_ELEMS; wl = WTl + WT_T_ELEMS;
        bias = bi; Y = pi; K = IMAGE_DIM;
    }
    const int m0 = (bid >> 3) * 32;
    const int n0 = (bid & 7) * 64 + nh * 32;
    const int Kh = K >> 1;
    const int nstep = Kh >> 5;               // 12 (text) / 16 (image)
    const int kbase = kh * Kh;

    const unsigned short* pah = xh + (long)(m0 + r16) * K + kbase + quad * 8;
    const unsigned short* pal = xl + (long)(m0 + r16) * K + kbase + quad * 8;
    const unsigned short* pbh = wh + (long)(n0 + r16) * K + kbase + quad * 8;
    const unsigned short* pbl = wl + (long)(n0 + r16) * K + kbase + quad * 8;
    const long rstep = (long)16 * K;

    f32x4 a00 = {0,0,0,0}, a01 = {0,0,0,0}, a10 = {0,0,0,0}, a11 = {0,0,0,0};

    // D=2 register prefetch: load next step's 8 fragments before MFMAing now
    bf16x8 Ah0 = *(const bf16x8*)(pah);
    bf16x8 Ah1 = *(const bf16x8*)(pah + rstep);
    bf16x8 Al0 = *(const bf16x8*)(pal);
    bf16x8 Al1 = *(const bf16x8*)(pal + rstep);
    bf16x8 Bh0 = *(const bf16x8*)(pbh);
    bf16x8 Bh1 = *(const bf16x8*)(pbh + rstep);
    bf16x8 Bl0 = *(const bf16x8*)(pbl);
    bf16x8 Bl1 = *(const bf16x8*)(pbl + rstep);

    for (int s = 0; s < nstep; ++s) {
        const int kn = (s + 1 < nstep) ? (s + 1) * 32 : 0;
        const bf16x8 nAh0 = *(const bf16x8*)(pah + kn);
        const bf16x8 nAh1 = *(const bf16x8*)(pah + rstep + kn);
        const bf16x8 nAl0 = *(const bf16x8*)(pal + kn);
        const bf16x8 nAl1 = *(const bf16x8*)(pal + rstep + kn);
        const bf16x8 nBh0 = *(const bf16x8*)(pbh + kn);
        const bf16x8 nBh1 = *(const bf16x8*)(pbh + rstep + kn);
        const bf16x8 nBl0 = *(const bf16x8*)(pbl + kn);
        const bf16x8 nBl1 = *(const bf16x8*)(pbl + rstep + kn);

        a00 = __builtin_amdgcn_mfma_f32_16x16x32_bf16(Ah0, Bh0, a00, 0, 0, 0);
        a01 = __builtin_amdgcn_mfma_f32_16x16x32_bf16(Ah0, Bh1, a01, 0, 0, 0);
        a10 = __builtin_amdgcn_mfma_f32_16x16x32_bf16(Ah1, Bh0, a10, 0, 0, 0);
        a11 = __builtin_amdgcn_mfma_f32_16x16x32_bf16(Ah1, Bh1, a11, 0, 0, 0);
        a00 = __builtin_amdgcn_mfma_f32_16x16x32_bf16(Ah0, Bl0, a00, 0, 0, 0);
        a01 = __builtin_amdgcn_mfma_f32_16x16x32_bf16(Ah0, Bl1, a01, 0, 0, 0);
        a10 = __builtin_amdgcn_mfma_f32_16x16x32_bf16(Ah1, Bl0, a10, 0, 0, 0);
        a11 = __builtin_amdgcn_mfma_f32_16x16x32_bf16(Ah1, Bl1, a11, 0, 0, 0);
        a00 = __builtin_amdgcn_mfma_f32_16x16x32_bf16(Al0, Bh0, a00, 0, 0, 0);
        a01 = __builtin_amdgcn_mfma_f32_16x16x32_bf16(Al0, Bh1, a01, 0, 0, 0);
        a10 = __builtin_amdgcn_mfma_f32_16x16x32_bf16(Al1, Bh0, a10, 0, 0, 0);
        a11 = __builtin_amdgcn_mfma_f32_16x16x32_bf16(Al1, Bh1, a11, 0, 0, 0);

        Ah0 = nAh0; Ah1 = nAh1; Al0 = nAl0; Al1 = nAl1;
        Bh0 = nBh0; Bh1 = nBh1; Bl0 = nBl0; Bl1 = nBl1;
    }

    // combine K-halves through LDS; kh==0 waves do bias + exp2 + store
    const int lc = nh * 32 + r16;
    if (kh == 1) {
        #pragma unroll
        for (int r = 0; r < 4; ++r) {
            part[(quad * 4 + r) * PSTRIDE + lc]           = a00[r];
            part[(quad * 4 + r) * PSTRIDE + lc + 16]      = a01[r];
            part[(quad * 4 + 16 + r) * PSTRIDE + lc]      = a10[r];
            part[(quad * 4 + 16 + r) * PSTRIDE + lc + 16] = a11[r];
        }
    }
    __syncthreads();
    if (kh == 0) {
        const int row0 = m0 + quad * 4;
        const float bv0 = bias[n0 + r16];
        const float bv1 = bias[n0 + 16 + r16];
        #pragma unroll
        for (int r = 0; r < 4; ++r) {
            const float v00 = (a00[r] + part[(quad * 4 + r) * PSTRIDE + lc]           + bv0) * EXP_SCALE;
            const float v01 = (a01[r] + part[(quad * 4 + r) * PSTRIDE + lc + 16]      + bv1) * EXP_SCALE;
            const float v10 = (a10[r] + part[(quad * 4 + 16 + r) * PSTRIDE + lc]      + bv0) * EXP_SCALE;
            const float v11 = (a11[r] + part[(quad * 4 + 16 + r) * PSTRIDE + lc + 16] + bv1) * EXP_SCALE;
            Y[(long)(row0 + r)      * HIDDEN + n0 + r16]      = FAST_EXP2(v00);
            Y[(long)(row0 + r)      * HIDDEN + n0 + 16 + r16] = FAST_EXP2(v01);
            Y[(long)(row0 + 16 + r) * HIDDEN + n0 + r16]      = FAST_EXP2(v10);
            Y[(long)(row0 + 16 + r) * HIDDEN + n0 + 16 + r16] = FAST_EXP2(v11);
        }
    }
}

// ---------------- Scores v8 ------------------------------------------------
// pt/pi now hold Et = exp2(EXP_SCALE*proj) (from mfma epilogue), so
// e^{2(pt+pi)} = Et*Ei and denom = fma(Et, Ei, 1) — no exp in inner loop.
__global__ __launch_bounds__(256, 8) void scores_kernel(const float* __restrict__ pt,
        const float* __restrict__ pi, const float* __restrict__ wa,
        const float* __restrict__ ba, float* __restrict__ scores)
{
    const int blk = blockIdx.x;
    const int bt = blk >> 1;
    const int half = blk & 1;
    const int b = bt >> 7;
    const int tid = threadIdx.x;
    const int lane = tid & 63, wave = tid >> 6;

    const float* ptrow = pt + (long)bt * HIDDEN + lane * 8;
    const float4 pA = *(const float4*)ptrow;
    const float4 pB = *(const float4*)(ptrow + 4);
    float4 wA = *(const float4*)(wa + lane * 8);
    float4 wB = *(const float4*)(wa + lane * 8 + 4);

    float S = wA.x + wA.y + wA.z + wA.w + wB.x + wB.y + wB.z + wB.w;
    #pragma unroll
    for (int off = 32; off; off >>= 1) S += __shfl_down(S, off);
    const float base = S + ba[0];

    wA.x *= -2.f; wA.y *= -2.f; wA.z *= -2.f; wA.w *= -2.f;
    wB.x *= -2.f; wB.y *= -2.f; wB.z *= -2.f; wB.w *= -2.f;

    const float* pib = pi + (long)b * I_TOK * HIDDEN + lane * 8;
    const int i0 = half * 98 + wave;
    const int iend = half * 98 + 98;

    float4 ca = *(const float4*)(pib + (long)i0 * HIDDEN);
    float4 cb = *(const float4*)(pib + (long)i0 * HIDDEN + 4);

    for (int i = i0; i < iend; i += 4) {
        const int inx = (i + 4 < iend) ? (i + 4) : i;
        const float4 na = *(const float4*)(pib + (long)inx * HIDDEN);
        const float4 nb = *(const float4*)(pib + (long)inx * HIDDEN + 4);

        float acc = 0.f;
        acc = fmaf(wA.x, FAST_RCP(fmaf(pA.x, ca.x, 1.f)), acc);
        acc = fmaf(wA.y, FAST_RCP(fmaf(pA.y, ca.y, 1.f)), acc);
        acc = fmaf(wA.z, FAST_RCP(fmaf(pA.z, ca.z, 1.f)), acc);
        acc = fmaf(wA.w, FAST_RCP(fmaf(pA.w, ca.w, 1.f)), acc);
        acc = fmaf(wB.x, FAST_RCP(fmaf(pB.x, cb.x, 1.f)), acc);
        acc = fmaf(wB.y, FAST_RCP(fmaf(pB.y, cb.y, 1.f)), acc);
        acc = fmaf(wB.z, FAST_RCP(fmaf(pB.z, cb.z, 1.f)), acc);
        acc = fmaf(wB.w, FAST_RCP(fmaf(pB.w, cb.w, 1.f)), acc);

        #pragma unroll
        for (int off = 32; off; off >>= 1) acc += __shfl_down(acc, off);
        if (lane == 0) scores[(long)bt * I_TOK + i] = base + acc;
        ca = na; cb = nb;
    }
}

// ---------------- Fused attended outputs (unchanged from R6/R7) ------------
__global__ __launch_bounds__(256) void att_kernel(const float* __restrict__ scores,
        const float* __restrict__ image, const float* __restrict__ text,
        float* __restrict__ out_text, float* __restrict__ out_img)
{
    const int tid = threadIdx.x, lane = tid & 63, wave = tid >> 6;

    if (blockIdx.x < 512) {
        const int bid = blockIdx.x;
        const int csplit = bid & 1;
        const int grp = bid >> 1;
        const int b = grp >> 5;
        const int t0 = (grp & 31) * 4;

        __shared__ float ps[I_TOK][4];
        {
            const float* srow = scores + ((long)(b * T + t0 + wave)) * I_TOK;
            const float s0 = srow[lane];
            const float s1 = srow[lane + 64];
            const float s2 = srow[lane + 128];
            const float s3 = (lane < 4) ? srow[lane + 192] : -INFINITY;
            float m = fmaxf(fmaxf(s0, s1), fmaxf(s2, s3));
            #pragma unroll
            for (int off = 32; off; off >>= 1) m = fmaxf(m, __shfl_xor(m, off));
            const float e0 = __expf(s0 - m);
            const float e1 = __expf(s1 - m);
            const float e2 = __expf(s2 - m);
            const float e3 = (lane < 4) ? __expf(s3 - m) : 0.f;
            float sum = e0 + e1 + e2 + e3;
            #pragma unroll
            for (int off = 32; off; off >>= 1) sum += __shfl_xor(sum, off);
            const float inv = __fdividef(1.0f, sum);
            ps[lane][wave] = e0 * inv;
            ps[lane + 64][wave] = e1 * inv;
            ps[lane + 128][wave] = e2 * inv;
            if (lane < 4) ps[lane + 192][wave] = e3 * inv;
        }
        __syncthreads();

        const float* img = image + (long)b * I_TOK * IMAGE_DIM + csplit * 512 + tid * 2;
        float a00 = 0.f, a01 = 0.f, a10 = 0.f, a11 = 0.f;
        float a20 = 0.f, a21 = 0.f, a30 = 0.f, a31 = 0.f;

        float2 v0 = *(const float2*)(img + 0 * IMAGE_DIM);
        float2 v1 = *(const float2*)(img + 1 * IMAGE_DIM);
        float2 v2 = *(const float2*)(img + 2 * IMAGE_DIM);
        float2 v3 = *(const float2*)(img + 3 * IMAGE_DIM);
        float4 p0 = *(const float4*)&ps[0][0];
        float4 p1 = *(const float4*)&ps[1][0];
        float4 p2 = *(const float4*)&ps[2][0];
        float4 p3 = *(const float4*)&ps[3][0];

        for (int g = 0; g < 49; ++g) {
            const int ib = (g + 1 < 49) ? (g + 1) * 4 : g * 4;
            const float2 w0 = *(const float2*)(img + (long)(ib + 0) * IMAGE_DIM);
            const float2 w1 = *(const float2*)(img + (long)(ib + 1) * IMAGE_DIM);
            const float2 w2 = *(const float2*)(img + (long)(ib + 2) * IMAGE_DIM);
            const float2 w3 = *(const float2*)(img + (long)(ib + 3) * IMAGE_DIM);
            const float4 r0 = *(const float4*)&ps[ib + 0][0];
            const float4 r1 = *(const float4*)&ps[ib + 1][0];
            const float4 r2 = *(const float4*)&ps[ib + 2][0];
            const float4 r3 = *(const float4*)&ps[ib + 3][0];
            a00 = fmaf(p0.x, v0.x, a00); a01 = fmaf(p0.x, v0.y, a01);
            a10 = fmaf(p0.y, v0.x, a10); a11 = fmaf(p0.y, v0.y, a11);
            a20 = fmaf(p0.z, v0.x, a20); a21 = fmaf(p0.z, v0.y, a21);
            a30 = fmaf(p0.w, v0.x, a30); a31 = fmaf(p0.w, v0.y, a31);
            a00 = fmaf(p1.x, v1.x, a00); a01 = fmaf(p1.x, v1.y, a01);
            a10 = fmaf(p1.y, v1.x, a10); a11 = fmaf(p1.y, v1.y, a11);
            a20 = fmaf(p1.z, v1.x, a20); a21 = fmaf(p1.z, v1.y, a21);
            a30 = fmaf(p1.w, v1.x, a30); a31 = fmaf(p1.w, v1.y, a31);
            a00 = fmaf(p2.x, v2.x, a00); a01 = fmaf(p2.x, v2.y, a01);
            a10 = fmaf(p2.y, v2.x, a10); a11 = fmaf(p2.y, v2.y, a11);
            a20 = fmaf(p2.z, v2.x, a20); a21 = fmaf(p2.z, v2.y, a21);
            a30 = fmaf(p2.w, v2.x, a30); a31 = fmaf(p2.w, v2.y, a31);
            a00 = fmaf(p3.x, v3.x, a00); a01 = fmaf(p3.x, v3.y, a01);
            a10 = fmaf(p3.y, v3.x, a10); a11 = fmaf(p3.y, v3.y, a11);
            a20 = fmaf(p3.z, v3.x, a20); a21 = fmaf(p3.z, v3.y, a21);
            a30 = fmaf(p3.w, v3.x, a30); a31 = fmaf(p3.w, v3.y, a31);
            v0 = w0; v1 = w1; v2 = w2; v3 = w3;
            p0 = r0; p1 = r1; p2 = r2; p3 = r3;
        }
        float* o = out_text + ((long)(b * T + t0)) * IMAGE_DIM + csplit * 512 + tid * 2;
        float2 w;
        w.x = a00; w.y = a01; *(float2*)(o + 0 * IMAGE_DIM) = w;
        w.x = a10; w.y = a11; *(float2*)(o + 1 * IMAGE_DIM) = w;
        w.x = a20; w.y = a21; *(float2*)(o + 2 * IMAGE_DIM) = w;
        w.x = a30; w.y = a31; *(float2*)(o + 3 * IMAGE_DIM) = w;
    } else {
        const int bid = blockIdx.x - 512;
        const int b = bid / (I_TOK / 4);
        const int i0 = (bid % (I_TOK / 4)) * 4;

        __shared__ float qs[T][4];
        {
            const float* sc = scores + (long)b * T * I_TOK + (i0 + wave);
            const float s0 = sc[(long)lane * I_TOK];
            const float s1 = sc[(long)(lane + 64) * I_TOK];
            float m = fmaxf(s0, s1);
            #pragma unroll
            for (int off = 32; off; off >>= 1) m = fmaxf(m, __shfl_xor(m, off));
            const float e0 = __expf(s0 - m);
            const float e1 = __expf(s1 - m);
            float sum = e0 + e1;
            #pragma unroll
            for (int off = 32; off; off >>= 1) sum += __shfl_xor(sum, off);
            const float inv = __fdividef(1.0f, sum);
            qs[lane][wave] = e0 * inv;
            qs[lane + 64][wave] = e1 * inv;
        }
        __syncthreads();

        const float* txt2 = text + (long)b * T * TEXT_DIM + tid * 2;
        const float* txt1 = text + (long)b * T * TEXT_DIM + 512 + tid;
        float a00=0.f,a01=0.f,a02=0.f, a10=0.f,a11=0.f,a12=0.f;
        float a20=0.f,a21=0.f,a22=0.f, a30=0.f,a31=0.f,a32=0.f;

        float2 u0 = *(const float2*)(txt2 + 0 * TEXT_DIM);
        float2 u1 = *(const float2*)(txt2 + 1 * TEXT_DIM);
        float  z0 = txt1[0 * TEXT_DIM];
        float  z1 = txt1[1 * TEXT_DIM];
        float4 q0 = *(const float4*)&qs[0][0];
        float4 q1 = *(const float4*)&qs[1][0];

        for (int g = 0; g < 64; ++g) {
            const int tb = (g + 1 < 64) ? (g + 1) * 2 : g * 2;
            const float2 nu0 = *(const float2*)(txt2 + (long)(tb + 0) * TEXT_DIM);
            const float2 nu1 = *(const float2*)(txt2 + (long)(tb + 1) * TEXT_DIM);
            const float  nz0 = txt1[(long)(tb + 0) * TEXT_DIM];
            const float  nz1 = txt1[(long)(tb + 1) * TEXT_DIM];
            const float4 nq0 = *(const float4*)&qs[tb + 0][0];
            const float4 nq1 = *(const float4*)&qs[tb + 1][0];
            a00 = fmaf(q0.x, u0.x, a00); a01 = fmaf(q0.x, u0.y, a01); a02 = fmaf(q0.x, z0, a02);
            a10 = fmaf(q0.y, u0.x, a10); a11 = fmaf(q0.y, u0.y, a11); a12 = fmaf(q0.y, z0, a12);
            a20 = fmaf(q0.z, u0.x, a20); a21 = fmaf(q0.z, u0.y, a21); a22 = fmaf(q0.z, z0, a22);
            a30 = fmaf(q0.w, u0.x, a30); a31 = fmaf(q0.w, u0.y, a31); a32 = fmaf(q0.w, z0, a32);
            a00 = fmaf(q1.x, u1.x, a00); a01 = fmaf(q1.x, u1.y, a01); a02 = fmaf(q1.x, z1, a02);
            a10 = fmaf(q1.y, u1.x, a10); a11 = fmaf(q1.y, u1.y, a11); a12 = fmaf(q1.y, z1, a12);
            a20 = fmaf(q1.z, u1.x, a20); a21 = fmaf(q1.z, u1.y, a21); a22 = fmaf(q1.z, z1, a22);
            a30 = fmaf(q1.w, u1.x, a30); a31 = fmaf(q1.w, u1.y, a31); a32 = fmaf(q1.w, z1, a32);
            u0 = nu0; u1 = nu1; z0 = nz0; z1 = nz1; q0 = nq0; q1 = nq1;
        }
        float* o = out_img + ((long)b * I_TOK + i0) * TEXT_DIM;
        float2 w;
        w.x = a00; w.y = a01; *(float2*)(o + 0 * TEXT_DIM + tid * 2) = w; o[0 * TEXT_DIM + 512 + tid] = a02;
        w.x = a10; w.y = a11; *(float2*)(o + 1 * TEXT_DIM + tid * 2) = w; o[1 * TEXT_DIM + 512 + tid] = a12;
        w.x = a20; w.y = a21; *(float2*)(o + 2 * TEXT_DIM + tid * 2) = w; o[2 * TEXT_DIM + 512 + tid] = a22;
        w.x = a30; w.y = a31; *(float2*)(o + 3 * TEXT_DIM + tid * 2) = w; o[3 * TEXT_DIM + 512 + tid] = a32;
    }
}

extern "C" void kernel_launch(void* const* d_in, const int* in_sizes, int n_in,
                              void* d_out, int out_size, void* d_ws, size_t ws_size,
                              hipStream_t stream) {
    const float* text  = (const float*)d_in[0];
    const float* image = (const float*)d_in[1];
    const float* Wt    = (const float*)d_in[2];
    const float* bt    = (const float*)d_in[3];
    const float* Wi    = (const float*)d_in[4];
    const float* bi    = (const float*)d_in[5];
    const float* wa    = (const float*)d_in[6];
    const float* ba    = (const float*)d_in[7];

    float* pt = (float*)d_ws;                       // Et = exp2-transformed
    float* pi = pt + (long)B * T * HIDDEN;          // Ei
    float* sc = pi + (long)B * I_TOK * HIDDEN;
    unsigned short* Xh  = (unsigned short*)(sc + (long)B * T * I_TOK);
    unsigned short* Xl  = Xh + X_ELEMS;
    unsigned short* WTh = Xl + X_ELEMS;
    unsigned short* WTl = WTh + W_ELEMS;

    float* out_text = (float*)d_out;                        // B*T*IMAGE_DIM
    float* out_img  = out_text + (long)B * T * IMAGE_DIM;   // B*I*TEXT_DIM

    prep_kernel<<<PREP_GRID, 256, 0, stream>>>(text, image, Wt, Wi, Xh, Xl, WTh, WTl);
    mfma_proj_kernel<<<GEMM_GRID, 256, 0, stream>>>(Xh, Xl, WTh, WTl, bt, bi, pt, pi);
    scores_kernel<<<2 * B * T, 256, 0, stream>>>(pt, pi, wa, ba, sc);
    att_kernel<<<512 + B * (I_TOK / 4), 256, 0, stream>>>(sc, image, text, out_text, out_img);
}

// Round 9
// 144.886 us; speedup vs baseline: 1.4841x; 1.1573x over previous
//
#include <hip/hip_runtime.h>
#include <math.h>

#define B 8
#define T 128
#define I_TOK 196
#define TEXT_DIM 768
#define IMAGE_DIM 1024
#define HIDDEN 512
#define EXP_SCALE 2.88539008177792681f   // 2*log2(e): exp(2x) = 2^(EXP_SCALE*x)

#if __has_builtin(__builtin_amdgcn_exp2f)
#define FAST_EXP2(x) __builtin_amdgcn_exp2f(x)
#else
#define FAST_EXP2(x) exp2f(x)
#endif
#if __has_builtin(__builtin_amdgcn_rcpf)
#define FAST_RCP(x) __builtin_amdgcn_rcpf(x)
#else
#define FAST_RCP(x) __fdividef(1.f, (x))
#endif
#if __has_builtin(__builtin_amdgcn_sched_barrier)
#define SCHED_FENCE() __builtin_amdgcn_sched_barrier(0)
#else
#define SCHED_FENCE()
#endif

typedef short bf16x8 __attribute__((ext_vector_type(8)));
typedef float f32x4 __attribute__((ext_vector_type(4)));

// ---- fragment-tiled layout geometry ---------------------------------------
// All MFMA operands stored as 16x32 tiles, 512 bf16 = 1KB each; within a
// tile, lane (r16 + 16*quad) owns 8 contiguous bf16 at tile_base + lane*8:
// element (row=r16, k=quad*8+j). GEMM loads are then one contiguous 1KB
// wave transaction (R8 post-mortem: row-major fragments touched 16 lines
// per load with 50% line waste -> vmem request-rate bound, 43.8us flat).
#define KT_T (TEXT_DIM / 32)     // 24 k-tiles (text)
#define KT_I (IMAGE_DIM / 32)    // 32 k-tiles (image)
#define MT_T (B * T / 16)        // 64 m-tiles (text rows)
#define MT_I (B * I_TOK / 16)    // 98 m-tiles (image rows)
#define NT   (HIDDEN / 16)       // 32 n-tiles (W columns)

#define XT_ELEMS (MT_T * KT_T * 512)       // 786432
#define XI_ELEMS (MT_I * KT_I * 512)       // 1605632
#define X_ELEMS  (XT_ELEMS + XI_ELEMS)
#define WT_T_ELEMS (NT * KT_T * 512)       // 393216
#define W_ELEMS (WT_T_ELEMS + NT * KT_I * 512)

#define XTILES_T (MT_T * KT_T)             // 1536
#define XTILES   (XTILES_T + MT_I * KT_I)  // 4672
#define WTILES_T (NT * KT_T)               // 768
#define WTILES   (WTILES_T + NT * KT_I)    // 1792
#define PREP_GRID ((XTILES + WTILES) / 4)  // 1616 blocks, 1 tile per wave

__device__ __forceinline__ unsigned short f2bf(float x) {
    unsigned int u = __float_as_uint(x);
    unsigned int r = u + 0x7FFFu + ((u >> 16) & 1u);   // RNE
    return (unsigned short)(r >> 16);
}
__device__ __forceinline__ float bf2f(unsigned short h) {
    return __uint_as_float(((unsigned int)h) << 16);
}

// ---------------- prep v9: split-bf16 + fragment-tiling --------------------
__global__ __launch_bounds__(256) void prep_kernel(
        const float* __restrict__ text, const float* __restrict__ image,
        const float* __restrict__ Wt, const float* __restrict__ Wi,
        unsigned short* __restrict__ Xh, unsigned short* __restrict__ Xl,
        unsigned short* __restrict__ WTh, unsigned short* __restrict__ WTl)
{
    const int tid = threadIdx.x;
    const int lane = tid & 63, wv = tid >> 6;
    const int r16 = lane & 15, quad = lane >> 4;
    const int id = blockIdx.x * 4 + wv;

    float v[8];
    unsigned short* oh;
    unsigned short* ol;
    long dst;

    if (id < XTILES) {
        // X tile: read 8 consecutive fp32 from row-major X
        const float* X; int K, mt, kt;
        if (id < XTILES_T) { X = text; K = TEXT_DIM; mt = id / KT_T; kt = id % KT_T; }
        else { const int i2 = id - XTILES_T; X = image; K = IMAGE_DIM; mt = i2 / KT_I; kt = i2 % KT_I; }
        const float* src = X + (long)(mt * 16 + r16) * K + kt * 32 + quad * 8;
        const float4 a = *(const float4*)src;
        const float4 b = *(const float4*)(src + 4);
        v[0]=a.x; v[1]=a.y; v[2]=a.z; v[3]=a.w; v[4]=b.x; v[5]=b.y; v[6]=b.z; v[7]=b.w;
        oh = (id < XTILES_T) ? Xh : Xh + XT_ELEMS;
        ol = (id < XTILES_T) ? Xl : Xl + XT_ELEMS;
        const long tile = (id < XTILES_T) ? id : (long)(id - XTILES_T);
        dst = tile * 512 + lane * 8;
    } else {
        // W tile: source W[k][n] row-major [K][512]; lane gathers 8 strided
        const int idw = id - XTILES;
        const float* W; int K, nt, kt;
        if (idw < WTILES_T) { W = Wt; K = TEXT_DIM; nt = idw / KT_T; kt = idw % KT_T; }
        else { const int i2 = idw - WTILES_T; W = Wi; K = IMAGE_DIM; nt = i2 / KT_I; kt = i2 % KT_I; }
        const float* src = W + (long)(kt * 32 + quad * 8) * HIDDEN + nt * 16 + r16;
        #pragma unroll
        for (int j = 0; j < 8; ++j) v[j] = src[(long)j * HIDDEN];
        oh = (idw < WTILES_T) ? WTh : WTh + WT_T_ELEMS;
        ol = (idw < WTILES_T) ? WTl : WTl + WT_T_ELEMS;
        const long tile = (idw < WTILES_T) ? idw : (long)(idw - WTILES_T);
        dst = tile * 512 + lane * 8;
    }

    uint4 hv, lv;
    unsigned int hh[8], ll[8];
    #pragma unroll
    for (int j = 0; j < 8; ++j) {
        hh[j] = f2bf(v[j]);
        ll[j] = f2bf(v[j] - bf2f((unsigned short)hh[j]));
    }
    hv.x = hh[0] | (hh[1] << 16); hv.y = hh[2] | (hh[3] << 16);
    hv.z = hh[4] | (hh[5] << 16); hv.w = hh[6] | (hh[7] << 16);
    lv.x = ll[0] | (ll[1] << 16); lv.y = ll[2] | (ll[3] << 16);
    lv.z = ll[4] | (ll[5] << 16); lv.w = ll[6] | (ll[7] << 16);
    *(uint4*)(oh + dst) = hv;
    *(uint4*)(ol + dst) = lv;
}

// ---------------- MFMA projections v9 --------------------------------------
// Same {nh,kh} wave split as R8 (2592 waves), but operands are fragment-
// tiled: every load = tile_base + lane*16B, one contiguous 1KB/wave.
// sched_barrier(0) pins the D=2 prefetch (R8: compiler sank it, VGPR=32).
#define GT_BLOCKS (32 * 8)
#define GI_BLOCKS (49 * 8)
#define GEMM_GRID (GT_BLOCKS + GI_BLOCKS)    // 648
#define PSTRIDE 66

__global__ __launch_bounds__(256, 2) void mfma_proj_kernel(
        const unsigned short* __restrict__ Xh, const unsigned short* __restrict__ Xl,
        const unsigned short* __restrict__ WTh, const unsigned short* __restrict__ WTl,
        const float* __restrict__ bt, const float* __restrict__ bi,
        float* __restrict__ pt, float* __restrict__ pi)
{
    __shared__ float part[32 * PSTRIDE];     // 8.4 KB K-half partials

    const int tid = threadIdx.x;
    const int lane = tid & 63, wv = tid >> 6;
    const int r16 = lane & 15, quad = lane >> 4;
    const int nh = wv & 1;                   // n-subtile
    const int kh = wv >> 1;                  // K-half

    int bid = blockIdx.x;
    const unsigned short *xh, *xl, *wh, *wl; const float* bias; float* Y;
    int ktiles;
    if (bid < GT_BLOCKS) {
        xh = Xh; xl = Xl; wh = WTh; wl = WTl; bias = bt; Y = pt; ktiles = KT_T;
    } else {
        bid -= GT_BLOCKS;
        xh = Xh + XT_ELEMS; xl = Xl + XT_ELEMS;
        wh = WTh + WT_T_ELEMS; wl = WTl + WT_T_ELEMS;
        bias = bi; Y = pi; ktiles = KT_I;
    }
    const int m0 = (bid >> 3) * 32;
    const int n0 = (bid & 7) * 64 + nh * 32;
    const int nstep = ktiles >> 1;           // 12 / 16
    const int kt0 = kh * nstep;
    const int mt0 = (bid >> 3) * 2;
    const int nt0 = (bid & 7) * 4 + nh * 2;

    const unsigned short* pa0 = xh + ((long)mt0 * ktiles + kt0) * 512 + lane * 8;
    const unsigned short* pa1 = pa0 + (long)ktiles * 512;
    const unsigned short* qa0 = xl + ((long)mt0 * ktiles + kt0) * 512 + lane * 8;
    const unsigned short* qa1 = qa0 + (long)ktiles * 512;
    const unsigned short* pb0 = wh + ((long)nt0 * ktiles + kt0) * 512 + lane * 8;
    const unsigned short* pb1 = pb0 + (long)ktiles * 512;
    const unsigned short* qb0 = wl + ((long)nt0 * ktiles + kt0) * 512 + lane * 8;
    const unsigned short* qb1 = qb0 + (long)ktiles * 512;

    f32x4 a00 = {0,0,0,0}, a01 = {0,0,0,0}, a10 = {0,0,0,0}, a11 = {0,0,0,0};

    bf16x8 Ah0 = *(const bf16x8*)(pa0);
    bf16x8 Ah1 = *(const bf16x8*)(pa1);
    bf16x8 Al0 = *(const bf16x8*)(qa0);
    bf16x8 Al1 = *(const bf16x8*)(qa1);
    bf16x8 Bh0 = *(const bf16x8*)(pb0);
    bf16x8 Bh1 = *(const bf16x8*)(pb1);
    bf16x8 Bl0 = *(const bf16x8*)(qb0);
    bf16x8 Bl1 = *(const bf16x8*)(qb1);

    for (int s = 0; s < nstep; ++s) {
        const long kn = (s + 1 < nstep) ? (long)(s + 1) * 512 : 0;
        const bf16x8 nAh0 = *(const bf16x8*)(pa0 + kn);
        const bf16x8 nAh1 = *(const bf16x8*)(pa1 + kn);
        const bf16x8 nAl0 = *(const bf16x8*)(qa0 + kn);
        const bf16x8 nAl1 = *(const bf16x8*)(qa1 + kn);
        const bf16x8 nBh0 = *(const bf16x8*)(pb0 + kn);
        const bf16x8 nBh1 = *(const bf16x8*)(pb1 + kn);
        const bf16x8 nBl0 = *(const bf16x8*)(qb0 + kn);
        const bf16x8 nBl1 = *(const bf16x8*)(qb1 + kn);
        SCHED_FENCE();

        a00 = __builtin_amdgcn_mfma_f32_16x16x32_bf16(Ah0, Bh0, a00, 0, 0, 0);
        a01 = __builtin_amdgcn_mfma_f32_16x16x32_bf16(Ah0, Bh1, a01, 0, 0, 0);
        a10 = __builtin_amdgcn_mfma_f32_16x16x32_bf16(Ah1, Bh0, a10, 0, 0, 0);
        a11 = __builtin_amdgcn_mfma_f32_16x16x32_bf16(Ah1, Bh1, a11, 0, 0, 0);
        a00 = __builtin_amdgcn_mfma_f32_16x16x32_bf16(Ah0, Bl0, a00, 0, 0, 0);
        a01 = __builtin_amdgcn_mfma_f32_16x16x32_bf16(Ah0, Bl1, a01, 0, 0, 0);
        a10 = __builtin_amdgcn_mfma_f32_16x16x32_bf16(Ah1, Bl0, a10, 0, 0, 0);
        a11 = __builtin_amdgcn_mfma_f32_16x16x32_bf16(Ah1, Bl1, a11, 0, 0, 0);
        a00 = __builtin_amdgcn_mfma_f32_16x16x32_bf16(Al0, Bh0, a00, 0, 0, 0);
        a01 = __builtin_amdgcn_mfma_f32_16x16x32_bf16(Al0, Bh1, a01, 0, 0, 0);
        a10 = __builtin_amdgcn_mfma_f32_16x16x32_bf16(Al1, Bh0, a10, 0, 0, 0);
        a11 = __builtin_amdgcn_mfma_f32_16x16x32_bf16(Al1, Bh1, a11, 0, 0, 0);
        SCHED_FENCE();

        Ah0 = nAh0; Ah1 = nAh1; Al0 = nAl0; Al1 = nAl1;
        Bh0 = nBh0; Bh1 = nBh1; Bl0 = nBl0; Bl1 = nBl1;
    }

    // combine K-halves through LDS; kh==0 waves do bias + exp2 + store
    const int lc = nh * 32 + r16;
    if (kh == 1) {
        #pragma unroll
        for (int r = 0; r < 4; ++r) {
            part[(quad * 4 + r) * PSTRIDE + lc]           = a00[r];
            part[(quad * 4 + r) * PSTRIDE + lc + 16]      = a01[r];
            part[(quad * 4 + 16 + r) * PSTRIDE + lc]      = a10[r];
            part[(quad * 4 + 16 + r) * PSTRIDE + lc + 16] = a11[r];
        }
    }
    __syncthreads();
    if (kh == 0) {
        const int row0 = m0 + quad * 4;
        const float bv0 = bias[n0 + r16];
        const float bv1 = bias[n0 + 16 + r16];
        #pragma unroll
        for (int r = 0; r < 4; ++r) {
            const float v00 = (a00[r] + part[(quad * 4 + r) * PSTRIDE + lc]           + bv0) * EXP_SCALE;
            const float v01 = (a01[r] + part[(quad * 4 + r) * PSTRIDE + lc + 16]      + bv1) * EXP_SCALE;
            const float v10 = (a10[r] + part[(quad * 4 + 16 + r) * PSTRIDE + lc]      + bv0) * EXP_SCALE;
            const float v11 = (a11[r] + part[(quad * 4 + 16 + r) * PSTRIDE + lc + 16] + bv1) * EXP_SCALE;
            Y[(long)(row0 + r)      * HIDDEN + n0 + r16]      = FAST_EXP2(v00);
            Y[(long)(row0 + r)      * HIDDEN + n0 + 16 + r16] = FAST_EXP2(v01);
            Y[(long)(row0 + 16 + r) * HIDDEN + n0 + r16]      = FAST_EXP2(v10);
            Y[(long)(row0 + 16 + r) * HIDDEN + n0 + 16 + r16] = FAST_EXP2(v11);
        }
    }
}

// ---------------- Scores v8 (unchanged) ------------------------------------
// pt/pi hold Et = exp2(EXP_SCALE*proj); denom = fma(Et, Ei, 1).
__global__ __launch_bounds__(256, 8) void scores_kernel(const float* __restrict__ pt,
        const float* __restrict__ pi, const float* __restrict__ wa,
        const float* __restrict__ ba, float* __restrict__ scores)
{
    const int blk = blockIdx.x;
    const int bt = blk >> 1;
    const int half = blk & 1;
    const int b = bt >> 7;
    const int tid = threadIdx.x;
    const int lane = tid & 63, wave = tid >> 6;

    const float* ptrow = pt + (long)bt * HIDDEN + lane * 8;
    const float4 pA = *(const float4*)ptrow;
    const float4 pB = *(const float4*)(ptrow + 4);
    float4 wA = *(const float4*)(wa + lane * 8);
    float4 wB = *(const float4*)(wa + lane * 8 + 4);

    float S = wA.x + wA.y + wA.z + wA.w + wB.x + wB.y + wB.z + wB.w;
    #pragma unroll
    for (int off = 32; off; off >>= 1) S += __shfl_down(S, off);
    const float base = S + ba[0];

    wA.x *= -2.f; wA.y *= -2.f; wA.z *= -2.f; wA.w *= -2.f;
    wB.x *= -2.f; wB.y *= -2.f; wB.z *= -2.f; wB.w *= -2.f;

    const float* pib = pi + (long)b * I_TOK * HIDDEN + lane * 8;
    const int i0 = half * 98 + wave;
    const int iend = half * 98 + 98;

    float4 ca = *(const float4*)(pib + (long)i0 * HIDDEN);
    float4 cb = *(const float4*)(pib + (long)i0 * HIDDEN + 4);

    for (int i = i0; i < iend; i += 4) {
        const int inx = (i + 4 < iend) ? (i + 4) : i;
        const float4 na = *(const float4*)(pib + (long)inx * HIDDEN);
        const float4 nb = *(const float4*)(pib + (long)inx * HIDDEN + 4);

        float acc = 0.f;
        acc = fmaf(wA.x, FAST_RCP(fmaf(pA.x, ca.x, 1.f)), acc);
        acc = fmaf(wA.y, FAST_RCP(fmaf(pA.y, ca.y, 1.f)), acc);
        acc = fmaf(wA.z, FAST_RCP(fmaf(pA.z, ca.z, 1.f)), acc);
        acc = fmaf(wA.w, FAST_RCP(fmaf(pA.w, ca.w, 1.f)), acc);
        acc = fmaf(wB.x, FAST_RCP(fmaf(pB.x, cb.x, 1.f)), acc);
        acc = fmaf(wB.y, FAST_RCP(fmaf(pB.y, cb.y, 1.f)), acc);
        acc = fmaf(wB.z, FAST_RCP(fmaf(pB.z, cb.z, 1.f)), acc);
        acc = fmaf(wB.w, FAST_RCP(fmaf(pB.w, cb.w, 1.f)), acc);

        #pragma unroll
        for (int off = 32; off; off >>= 1) acc += __shfl_down(acc, off);
        if (lane == 0) scores[(long)bt * I_TOK + i] = base + acc;
        ca = na; cb = nb;
    }
}

// ---------------- Fused attended outputs (unchanged) -----------------------
__global__ __launch_bounds__(256) void att_kernel(const float* __restrict__ scores,
        const float* __restrict__ image, const float* __restrict__ text,
        float* __restrict__ out_text, float* __restrict__ out_img)
{
    const int tid = threadIdx.x, lane = tid & 63, wave = tid >> 6;

    if (blockIdx.x < 512) {
        const int bid = blockIdx.x;
        const int csplit = bid & 1;
        const int grp = bid >> 1;
        const int b = grp >> 5;
        const int t0 = (grp & 31) * 4;

        __shared__ float ps[I_TOK][4];
        {
            const float* srow = scores + ((long)(b * T + t0 + wave)) * I_TOK;
            const float s0 = srow[lane];
            const float s1 = srow[lane + 64];
            const float s2 = srow[lane + 128];
            const float s3 = (lane < 4) ? srow[lane + 192] : -INFINITY;
            float m = fmaxf(fmaxf(s0, s1), fmaxf(s2, s3));
            #pragma unroll
            for (int off = 32; off; off >>= 1) m = fmaxf(m, __shfl_xor(m, off));
            const float e0 = __expf(s0 - m);
            const float e1 = __expf(s1 - m);
            const float e2 = __expf(s2 - m);
            const float e3 = (lane < 4) ? __expf(s3 - m) : 0.f;
            float sum = e0 + e1 + e2 + e3;
            #pragma unroll
            for (int off = 32; off; off >>= 1) sum += __shfl_xor(sum, off);
            const float inv = __fdividef(1.0f, sum);
            ps[lane][wave] = e0 * inv;
            ps[lane + 64][wave] = e1 * inv;
            ps[lane + 128][wave] = e2 * inv;
            if (lane < 4) ps[lane + 192][wave] = e3 * inv;
        }
        __syncthreads();

        const float* img = image + (long)b * I_TOK * IMAGE_DIM + csplit * 512 + tid * 2;
        float a00 = 0.f, a01 = 0.f, a10 = 0.f, a11 = 0.f;
        float a20 = 0.f, a21 = 0.f, a30 = 0.f, a31 = 0.f;

        float2 v0 = *(const float2*)(img + 0 * IMAGE_DIM);
        float2 v1 = *(const float2*)(img + 1 * IMAGE_DIM);
        float2 v2 = *(const float2*)(img + 2 * IMAGE_DIM);
        float2 v3 = *(const float2*)(img + 3 * IMAGE_DIM);
        float4 p0 = *(const float4*)&ps[0][0];
        float4 p1 = *(const float4*)&ps[1][0];
        float4 p2 = *(const float4*)&ps[2][0];
        float4 p3 = *(const float4*)&ps[3][0];

        for (int g = 0; g < 49; ++g) {
            const int ib = (g + 1 < 49) ? (g + 1) * 4 : g * 4;
            const float2 w0 = *(const float2*)(img + (long)(ib + 0) * IMAGE_DIM);
            const float2 w1 = *(const float2*)(img + (long)(ib + 1) * IMAGE_DIM);
            const float2 w2 = *(const float2*)(img + (long)(ib + 2) * IMAGE_DIM);
            const float2 w3 = *(const float2*)(img + (long)(ib + 3) * IMAGE_DIM);
            const float4 r0 = *(const float4*)&ps[ib + 0][0];
            const float4 r1 = *(const float4*)&ps[ib + 1][0];
            const float4 r2 = *(const float4*)&ps[ib + 2][0];
            const float4 r3 = *(const float4*)&ps[ib + 3][0];
            a00 = fmaf(p0.x, v0.x, a00); a01 = fmaf(p0.x, v0.y, a01);
            a10 = fmaf(p0.y, v0.x, a10); a11 = fmaf(p0.y, v0.y, a11);
            a20 = fmaf(p0.z, v0.x, a20); a21 = fmaf(p0.z, v0.y, a21);
            a30 = fmaf(p0.w, v0.x, a30); a31 = fmaf(p0.w, v0.y, a31);
            a00 = fmaf(p1.x, v1.x, a00); a01 = fmaf(p1.x, v1.y, a01);
            a10 = fmaf(p1.y, v1.x, a10); a11 = fmaf(p1.y, v1.y, a11);
            a20 = fmaf(p1.z, v1.x, a20); a21 = fmaf(p1.z, v1.y, a21);
            a30 = fmaf(p1.w, v1.x, a30); a31 = fmaf(p1.w, v1.y, a31);
            a00 = fmaf(p2.x, v2.x, a00); a01 = fmaf(p2.x, v2.y, a01);
            a10 = fmaf(p2.y, v2.x, a10); a11 = fmaf(p2.y, v2.y, a11);
            a20 = fmaf(p2.z, v2.x, a20); a21 = fmaf(p2.z, v2.y, a21);
            a30 = fmaf(p2.w, v2.x, a30); a31 = fmaf(p2.w, v2.y, a31);
            a00 = fmaf(p3.x, v3.x, a00); a01 = fmaf(p3.x, v3.y, a01);
            a10 = fmaf(p3.y, v3.x, a10); a11 = fmaf(p3.y, v3.y, a11);
            a20 = fmaf(p3.z, v3.x, a20); a21 = fmaf(p3.z, v3.y, a21);
            a30 = fmaf(p3.w, v3.x, a30); a31 = fmaf(p3.w, v3.y, a31);
            v0 = w0; v1 = w1; v2 = w2; v3 = w3;
            p0 = r0; p1 = r1; p2 = r2; p3 = r3;
        }
        float* o = out_text + ((long)(b * T + t0)) * IMAGE_DIM + csplit * 512 + tid * 2;
        float2 w;
        w.x = a00; w.y = a01; *(float2*)(o + 0 * IMAGE_DIM) = w;
        w.x = a10; w.y = a11; *(float2*)(o + 1 * IMAGE_DIM) = w;
        w.x = a20; w.y = a21; *(float2*)(o + 2 * IMAGE_DIM) = w;
        w.x = a30; w.y = a31; *(float2*)(o + 3 * IMAGE_DIM) = w;
    } else {
        const int bid = blockIdx.x - 512;
        const int b = bid / (I_TOK / 4);
        const int i0 = (bid % (I_TOK / 4)) * 4;

        __shared__ float qs[T][4];
        {
            const float* sc = scores + (long)b * T * I_TOK + (i0 + wave);
            const float s0 = sc[(long)lane * I_TOK];
            const float s1 = sc[(long)(lane + 64) * I_TOK];
            float m = fmaxf(s0, s1);
            #pragma unroll
            for (int off = 32; off; off >>= 1) m = fmaxf(m, __shfl_xor(m, off));
            const float e0 = __expf(s0 - m);
            const float e1 = __expf(s1 - m);
            float sum = e0 + e1;
            #pragma unroll
            for (int off = 32; off; off >>= 1) sum += __shfl_xor(sum, off);
            const float inv = __fdividef(1.0f, sum);
            qs[lane][wave] = e0 * inv;
            qs[lane + 64][wave] = e1 * inv;
        }
        __syncthreads();

        const float* txt2 = text + (long)b * T * TEXT_DIM + tid * 2;
        const float* txt1 = text + (long)b * T * TEXT_DIM + 512 + tid;
        float a00=0.f,a01=0.f,a02=0.f, a10=0.f,a11=0.f,a12=0.f;
        float a20=0.f,a21=0.f,a22=0.f, a30=0.f,a31=0.f,a32=0.f;

        float2 u0 = *(const float2*)(txt2 + 0 * TEXT_DIM);
        float2 u1 = *(const float2*)(txt2 + 1 * TEXT_DIM);
        float  z0 = txt1[0 * TEXT_DIM];
        float  z1 = txt1[1 * TEXT_DIM];
        float4 q0 = *(const float4*)&qs[0][0];
        float4 q1 = *(const float4*)&qs[1][0];

        for (int g = 0; g < 64; ++g) {
            const int tb = (g + 1 < 64) ? (g + 1) * 2 : g * 2;
            const float2 nu0 = *(const float2*)(txt2 + (long)(tb + 0) * TEXT_DIM);
            const float2 nu1 = *(const float2*)(txt2 + (long)(tb + 1) * TEXT_DIM);
            const float  nz0 = txt1[(long)(tb + 0) * TEXT_DIM];
            const float  nz1 = txt1[(long)(tb + 1) * TEXT_DIM];
            const float4 nq0 = *(const float4*)&qs[tb + 0][0];
            const float4 nq1 = *(const float4*)&qs[tb + 1][0];
            a00 = fmaf(q0.x, u0.x, a00); a01 = fmaf(q0.x, u0.y, a01); a02 = fmaf(q0.x, z0, a02);
            a10 = fmaf(q0.y, u0.x, a10); a11 = fmaf(q0.y, u0.y, a11); a12 = fmaf(q0.y, z0, a12);
            a20 = fmaf(q0.z, u0.x, a20); a21 = fmaf(q0.z, u0.y, a21); a22 = fmaf(q0.z, z0, a22);
            a30 = fmaf(q0.w, u0.x, a30); a31 = fmaf(q0.w, u0.y, a31); a32 = fmaf(q0.w, z0, a32);
            a00 = fmaf(q1.x, u1.x, a00); a01 = fmaf(q1.x, u1.y, a01); a02 = fmaf(q1.x, z1, a02);
            a10 = fmaf(q1.y, u1.x, a10); a11 = fmaf(q1.y, u1.y, a11); a12 = fmaf(q1.y, z1, a12);
            a20 = fmaf(q1.z, u1.x, a20); a21 = fmaf(q1.z, u1.y, a21); a22 = fmaf(q1.z, z1, a22);
            a30 = fmaf(q1.w, u1.x, a30); a31 = fmaf(q1.w, u1.y, a31); a32 = fmaf(q1.w, z1, a32);
            u0 = nu0; u1 = nu1; z0 = nz0; z1 = nz1; q0 = nq0; q1 = nq1;
        }
        float* o = out_img + ((long)b * I_TOK + i0) * TEXT_DIM;
        float2 w;
        w.x = a00; w.y = a01; *(float2*)(o + 0 * TEXT_DIM + tid * 2) = w; o[0 * TEXT_DIM + 512 + tid] = a02;
        w.x = a10; w.y = a11; *(float2*)(o + 1 * TEXT_DIM + tid * 2) = w; o[1 * TEXT_DIM + 512 + tid] = a12;
        w.x = a20; w.y = a21; *(float2*)(o + 2 * TEXT_DIM + tid * 2) = w; o[2 * TEXT_DIM + 512 + tid] = a22;
        w.x = a30; w.y = a31; *(float2*)(o + 3 * TEXT_DIM + tid * 2) = w; o[3 * TEXT_DIM + 512 + tid] = a32;
    }
}

extern "C" void kernel_launch(void* const* d_in, const int* in_sizes, int n_in,
                              void* d_out, int out_size, void* d_ws, size_t ws_size,
                              hipStream_t stream) {
    const float* text  = (const float*)d_in[0];
    const float* image = (const float*)d_in[1];
    const float* Wt    = (const float*)d_in[2];
    const float* bt    = (const float*)d_in[3];
    const float* Wi    = (const float*)d_in[4];
    const float* bi    = (const float*)d_in[5];
    const float* wa    = (const float*)d_in[6];
    const float* ba    = (const float*)d_in[7];

    float* pt = (float*)d_ws;                       // Et = exp2-transformed
    float* pi = pt + (long)B * T * HIDDEN;          // Ei
    float* sc = pi + (long)B * I_TOK * HIDDEN;
    unsigned short* Xh  = (unsigned short*)(sc + (long)B * T * I_TOK);
    unsigned short* Xl  = Xh + X_ELEMS;
    unsigned short* WTh = Xl + X_ELEMS;
    unsigned short* WTl = WTh + W_ELEMS;

    float* out_text = (float*)d_out;                        // B*T*IMAGE_DIM
    float* out_img  = out_text + (long)B * T * IMAGE_DIM;   // B*I*TEXT_DIM

    prep_kernel<<<PREP_GRID, 256, 0, stream>>>(text, image, Wt, Wi, Xh, Xl, WTh, WTl);
    mfma_proj_kernel<<<GEMM_GRID, 256, 0, stream>>>(Xh, Xl, WTh, WTl, bt, bi, pt, pi);
    scores_kernel<<<2 * B * T, 256, 0, stream>>>(pt, pi, wa, ba, sc);
    att_kernel<<<512 + B * (I_TOK / 4), 256, 0, stream>>>(sc, image, text, out_text, out_img);
}